// Round 1
// baseline (1148.321 us; speedup 1.0000x reference)
//
#include <hip/hip_runtime.h>
#include <math.h>

#define N_NODES 40000
#define E_EDGES 60000
#define R_REL 6
#define IN_F 32
#define HID_F 128
#define B_GRAPHS 2000
#define NODES_PER_G 20
#define HC 256            // H*C = 2*128
#define NEG_SLOPE 0.2f

// ---------------- adjacency: linked-list by dst, built per call ----------------
__global__ __launch_bounds__(256) void build_links_kernel(
    const int* __restrict__ ei, int* __restrict__ head, int* __restrict__ nxt)
{
    int idx = blockIdx.x * 256 + threadIdx.x;
    if (idx >= R_REL * E_EDGES) return;
    int r = idx / E_EDGES;
    int e = idx - r * E_EDGES;
    int dst = ei[(size_t)r * 2 * E_EDGES + E_EDGES + e];   // edge_index[r][1][e]
    int old = atomicExch(&head[r * N_NODES + dst], e);
    nxt[(size_t)r * E_EDGES + e] = old;
}

// ---------------- fused XL|XR transform: out[n, 0:256]=A@Wl+bl, [256:512]=A@Wr+br
template <int K>
__global__ __launch_bounds__(256) void gemm_xlr_kernel(
    const float* __restrict__ A,
    const float* __restrict__ Wl, const float* __restrict__ Wr,
    const float* __restrict__ bl, const float* __restrict__ br,
    float* __restrict__ out)
{
    __shared__ float As[32][65];
    __shared__ float Bs[32][64];
    int tid = threadIdx.x;
    int tx = tid & 15, ty = tid >> 4;
    int row0 = blockIdx.x * 64;
    int col0 = blockIdx.y * 64;       // 0..511 in steps of 64; never straddles 256
    const float* Bsrc = (col0 < 256) ? Wl : Wr;
    const float* bias = (col0 < 256) ? bl : br;
    int colbase = (col0 < 256) ? col0 : col0 - 256;
    float acc[4][4] = {};
    for (int k0 = 0; k0 < K; k0 += 32) {
        int ak = tid & 31, arow = tid >> 5;
#pragma unroll
        for (int i = 0; i < 8; i++)
            As[ak][arow + 8 * i] = A[(size_t)(row0 + arow + 8 * i) * K + k0 + ak];
        int bcol = tid & 63, bk = tid >> 6;
#pragma unroll
        for (int i = 0; i < 8; i++)
            Bs[bk + 4 * i][bcol] = Bsrc[(size_t)(k0 + bk + 4 * i) * HC + colbase + bcol];
        __syncthreads();
#pragma unroll
        for (int kk = 0; kk < 32; kk++) {
            float a[4], b[4];
#pragma unroll
            for (int i = 0; i < 4; i++) a[i] = As[kk][ty * 4 + i];
#pragma unroll
            for (int j = 0; j < 4; j++) b[j] = Bs[kk][tx * 4 + j];
#pragma unroll
            for (int i = 0; i < 4; i++)
#pragma unroll
                for (int j = 0; j < 4; j++)
                    acc[i][j] = fmaf(a[i], b[j], acc[i][j]);
        }
        __syncthreads();
    }
#pragma unroll
    for (int i = 0; i < 4; i++) {
        int row = row0 + ty * 4 + i;
#pragma unroll
        for (int j = 0; j < 4; j++) {
            int col = col0 + tx * 4 + j;
            out[(size_t)row * 512 + col] = acc[i][j] + bias[colbase + tx * 4 + j];
        }
    }
}

// ---------------- fused GATv2 edge stage: one wave per dst, online softmax ----
// lane l owns channels {l, l+64} of head0 and {l, l+64} of head1
// XLR layout: [n][0:256]=xl (h*128+c), [n][256:512]=xr
__global__ __launch_bounds__(256) void gat_kernel(
    const float* __restrict__ XLR,
    const int* __restrict__ head, const int* __restrict__ nxt,
    const int* __restrict__ srcs,
    const float* __restrict__ att,   // [2][128] for this relation
    const float* __restrict__ bias,  // [128]
    float* __restrict__ hacc,        // [N,128]
    int accumulate)
{
    int gtid = blockIdx.x * 256 + threadIdx.x;
    int d = gtid >> 6;
    int lane = threadIdx.x & 63;
    if (d >= N_NODES) return;

    const float* xrp = XLR + (size_t)d * 512 + 256;
    float xr0 = xrp[lane], xr1 = xrp[lane + 64], xr2 = xrp[lane + 128], xr3 = xrp[lane + 192];
    float a0 = att[lane], a1 = att[lane + 64], a2 = att[lane + 128], a3 = att[lane + 192];

    float m0 = -1e30f, m1 = -1e30f, s0 = 0.f, s1 = 0.f;
    float acc00 = 0.f, acc01 = 0.f, acc10 = 0.f, acc11 = 0.f;

    int e = head[d];
    int src = d;                    // implicit self-loop processed first
    while (true) {
        const float* xlp = XLR + (size_t)src * 512;
        float xl0 = xlp[lane], xl1 = xlp[lane + 64], xl2 = xlp[lane + 128], xl3 = xlp[lane + 192];
        float t0 = xl0 + xr0; t0 = t0 > 0.f ? t0 : NEG_SLOPE * t0;
        float t1 = xl1 + xr1; t1 = t1 > 0.f ? t1 : NEG_SLOPE * t1;
        float t2 = xl2 + xr2; t2 = t2 > 0.f ? t2 : NEG_SLOPE * t2;
        float t3 = xl3 + xr3; t3 = t3 > 0.f ? t3 : NEG_SLOPE * t3;
        float p0 = t0 * a0 + t1 * a1;     // head0 partial dot
        float p1 = t2 * a2 + t3 * a3;     // head1 partial dot
#pragma unroll
        for (int off = 32; off >= 1; off >>= 1) {
            p0 += __shfl_xor(p0, off, 64);
            p1 += __shfl_xor(p1, off, 64);
        }
        // online softmax update, head 0
        float mn = fmaxf(m0, p0);
        float sc = __expf(m0 - mn);
        float w  = __expf(p0 - mn);
        s0 = s0 * sc + w;
        acc00 = acc00 * sc + w * xl0;
        acc01 = acc01 * sc + w * xl1;
        m0 = mn;
        // head 1
        mn = fmaxf(m1, p1);
        sc = __expf(m1 - mn);
        w  = __expf(p1 - mn);
        s1 = s1 * sc + w;
        acc10 = acc10 * sc + w * xl2;
        acc11 = acc11 * sc + w * xl3;
        m1 = mn;

        if (e < 0) break;
        src = srcs[e];
        e = nxt[e];
    }
    float o0 = 0.5f * (acc00 / s0 + acc10 / s1) + bias[lane];
    float o1 = 0.5f * (acc01 / s0 + acc11 / s1) + bias[lane + 64];
    float* hp = hacc + (size_t)d * 128;
    if (accumulate) { hp[lane] += o0; hp[lane + 64] += o1; }
    else            { hp[lane]  = o0; hp[lane + 64]  = o1; }
}

// ---------------- tanh + layernorm, one wave per node ----------------
__global__ __launch_bounds__(256) void tanh_ln_kernel(
    const float* __restrict__ hacc, const float* __restrict__ g,
    const float* __restrict__ b, float* __restrict__ hout)
{
    int gtid = blockIdx.x * 256 + threadIdx.x;
    int n = gtid >> 6;
    int lane = threadIdx.x & 63;
    if (n >= N_NODES) return;
    const float* hp = hacc + (size_t)n * 128;
    float v0 = tanhf(hp[lane]), v1 = tanhf(hp[lane + 64]);
    float sum = v0 + v1, sq = v0 * v0 + v1 * v1;
#pragma unroll
    for (int off = 32; off >= 1; off >>= 1) {
        sum += __shfl_xor(sum, off, 64);
        sq  += __shfl_xor(sq, off, 64);
    }
    float mean = sum * (1.f / 128.f);
    float var = sq * (1.f / 128.f) - mean * mean;
    float rstd = rsqrtf(var + 1e-5f);
    float* op = hout + (size_t)n * 128;
    op[lane]      = (v0 - mean) * rstd * g[lane] + b[lane];
    op[lane + 64] = (v1 - mean) * rstd * g[lane + 64] + b[lane + 64];
}

// ---------------- attention pooling: one wave per graph (20 contiguous nodes) --
__global__ __launch_bounds__(256) void pool_kernel(
    const float* __restrict__ h, const float* __restrict__ query,
    float* __restrict__ gout)
{
    int gtid = blockIdx.x * 256 + threadIdx.x;
    int bg = gtid >> 6;
    int lane = threadIdx.x & 63;
    if (bg >= B_GRAPHS) return;
    float q0 = query[lane], q1 = query[lane + 64];
    float mx = -1e30f, ssum = 0.f, g0 = 0.f, g1 = 0.f;
    for (int i = 0; i < NODES_PER_G; i++) {
        const float* hp = h + (size_t)(bg * NODES_PER_G + i) * 128;
        float h0 = hp[lane], h1 = hp[lane + 64];
        float p = h0 * q0 + h1 * q1;
#pragma unroll
        for (int off = 32; off >= 1; off >>= 1) p += __shfl_xor(p, off, 64);
        float mn = fmaxf(mx, p);
        float sc = __expf(mx - mn), w = __expf(p - mn);
        ssum = ssum * sc + w;
        g0 = g0 * sc + w * h0;
        g1 = g1 * sc + w * h1;
        mx = mn;
    }
    gout[(size_t)bg * 128 + lane]      = g0 / ssum;
    gout[(size_t)bg * 128 + lane + 64] = g1 / ssum;
}

// ---------------- final projection: out = g @ projW + projb ----------------
__global__ __launch_bounds__(128) void proj_kernel(
    const float* __restrict__ g, const float* __restrict__ W,
    const float* __restrict__ bias, float* __restrict__ out)
{
    int bg = blockIdx.x;
    int o = threadIdx.x;
    const float* gp = g + (size_t)bg * 128;
    float acc = bias[o];
    for (int k = 0; k < 128; k++) acc = fmaf(gp[k], W[k * 128 + o], acc);
    out[(size_t)bg * 128 + o] = acc;
}

extern "C" void kernel_launch(void* const* d_in, const int* in_sizes, int n_in,
                              void* d_out, int out_size, void* d_ws, size_t ws_size,
                              hipStream_t stream)
{
    const float* x     = (const float*)d_in[0];
    const int*   ei    = (const int*)d_in[1];
    // d_in[2] = batch (contiguous arange//20, exploited structurally)
    const float* Wl1   = (const float*)d_in[3];
    const float* bl1   = (const float*)d_in[4];
    const float* Wr1   = (const float*)d_in[5];
    const float* br1   = (const float*)d_in[6];
    const float* att1  = (const float*)d_in[7];
    const float* bias1 = (const float*)d_in[8];
    const float* Wl2   = (const float*)d_in[9];
    const float* bl2   = (const float*)d_in[10];
    const float* Wr2   = (const float*)d_in[11];
    const float* br2   = (const float*)d_in[12];
    const float* att2  = (const float*)d_in[13];
    const float* bias2 = (const float*)d_in[14];
    const float* ln1g  = (const float*)d_in[15];
    const float* ln1b  = (const float*)d_in[16];
    const float* ln2g  = (const float*)d_in[17];
    const float* ln2b  = (const float*)d_in[18];
    const float* query = (const float*)d_in[19];
    const float* projW = (const float*)d_in[20];
    const float* projb = (const float*)d_in[21];
    float* out = (float*)d_out;

    // workspace layout (all regions fully rewritten every call — poison-safe)
    float* xlr  = (float*)d_ws;                        // N*512 f32 = 81.92 MB
    float* hacc = xlr + (size_t)N_NODES * 512;         // N*128 f32 = 20.48 MB
    float* h1   = hacc + (size_t)N_NODES * 128;        // N*128 f32 = 20.48 MB
    int* headp  = (int*)(h1 + (size_t)N_NODES * 128);  // R*N int   = 0.96 MB
    int* nextp  = headp + R_REL * N_NODES;             // R*E int   = 1.44 MB
    float* gb   = xlr;                                 // alias: pooled g [B,128]

    hipMemsetAsync(headp, 0xFF, sizeof(int) * R_REL * N_NODES, stream);
    build_links_kernel<<<(R_REL * E_EDGES + 255) / 256, 256, 0, stream>>>(ei, headp, nextp);

    dim3 ggrid(N_NODES / 64, 8);
    // ---- layer 1 ----
    for (int r = 0; r < R_REL; r++) {
        gemm_xlr_kernel<IN_F><<<ggrid, 256, 0, stream>>>(
            x, Wl1 + (size_t)r * IN_F * HC, Wr1 + (size_t)r * IN_F * HC,
            bl1 + r * HC, br1 + r * HC, xlr);
        gat_kernel<<<N_NODES / 4, 256, 0, stream>>>(
            xlr, headp + r * N_NODES, nextp + (size_t)r * E_EDGES,
            ei + (size_t)r * 2 * E_EDGES, att1 + r * HC, bias1 + r * 128, hacc, r > 0);
    }
    tanh_ln_kernel<<<N_NODES / 4, 256, 0, stream>>>(hacc, ln1g, ln1b, h1);
    // ---- layer 2 ----
    for (int r = 0; r < R_REL; r++) {
        gemm_xlr_kernel<HID_F><<<ggrid, 256, 0, stream>>>(
            h1, Wl2 + (size_t)r * HID_F * HC, Wr2 + (size_t)r * HID_F * HC,
            bl2 + r * HC, br2 + r * HC, xlr);
        gat_kernel<<<N_NODES / 4, 256, 0, stream>>>(
            xlr, headp + r * N_NODES, nextp + (size_t)r * E_EDGES,
            ei + (size_t)r * 2 * E_EDGES, att2 + r * HC, bias2 + r * 128, hacc, r > 0);
    }
    tanh_ln_kernel<<<N_NODES / 4, 256, 0, stream>>>(hacc, ln2g, ln2b, h1);  // h2 over h1
    // ---- pooling + projection ----
    pool_kernel<<<B_GRAPHS / 4, 256, 0, stream>>>(h1, query, gb);
    proj_kernel<<<B_GRAPHS, 128, 0, stream>>>(gb, projW, projb, out);
}

// Round 2
// 695.732 us; speedup vs baseline: 1.6505x; 1.6505x over previous
//
#include <hip/hip_runtime.h>
#include <math.h>

#define N_NODES 40000
#define E_EDGES 60000
#define R_REL 6
#define IN_F 32
#define HID_F 128
#define B_GRAPHS 2000
#define NODES_PER_G 20
#define NEG_SLOPE 0.2f

typedef __bf16 bf16x8 __attribute__((ext_vector_type(8)));
typedef float f32x4 __attribute__((ext_vector_type(4)));

__device__ __forceinline__ unsigned f2bfbits(float f) {
    unsigned u = __builtin_bit_cast(unsigned, f);
    return (u + 0x7FFFu + ((u >> 16) & 1u)) >> 16;   // RNE
}
__device__ __forceinline__ float bflo(unsigned u) { return __builtin_bit_cast(float, u << 16); }
__device__ __forceinline__ float bfhi(unsigned u) { return __builtin_bit_cast(float, u & 0xFFFF0000u); }

// ---------------- adjacency: linked-list by dst ----------------
__global__ __launch_bounds__(256) void build_links_kernel(
    const int* __restrict__ ei, int* __restrict__ head, int* __restrict__ nxt)
{
    int idx = blockIdx.x * 256 + threadIdx.x;
    if (idx >= R_REL * E_EDGES) return;
    int r = idx / E_EDGES;
    int e = idx - r * E_EDGES;
    int dst = ei[(size_t)r * 2 * E_EDGES + E_EDGES + e];
    int old = atomicExch(&head[r * N_NODES + dst], e);
    nxt[(size_t)r * E_EDGES + e] = old;
}

// ---------------- prep: fp32 -> bf16 pairwise ----------------
__global__ __launch_bounds__(256) void cvt_bf16_kernel(
    const float* __restrict__ src, unsigned* __restrict__ dst, int npairs)
{
    int i = blockIdx.x * 256 + threadIdx.x;
    if (i >= npairs) return;
    float2 v = *(const float2*)(src + 2 * i);
    dst[i] = f2bfbits(v.x) | (f2bfbits(v.y) << 16);
}

// ---------------- prep: W[r][k][256] (l|r) -> Bt[r][512][K] bf16, bias cat ----
__global__ __launch_bounds__(256) void prep_w_kernel(
    const float* __restrict__ Wl, const float* __restrict__ Wr,
    const float* __restrict__ bl, const float* __restrict__ br,
    unsigned short* __restrict__ Bt, float* __restrict__ bcat, int K)
{
    int idx = blockIdx.x * 256 + threadIdx.x;
    if (idx >= R_REL * 512 * K) return;
    int k = idx % K;
    int rn = idx / K;
    int n = rn % 512;
    int r = rn / 512;
    int nn = n & 255;
    const float* W = (n < 256) ? Wl : Wr;
    float w = W[((size_t)r * K + k) * 256 + nn];
    Bt[idx] = (unsigned short)f2bfbits(w);
    if (k == 0)
        bcat[rn] = (n < 256) ? bl[r * 256 + nn] : br[r * 256 + nn];
}

// ---------------- MFMA GEMM: C[40000][512]bf16 = A[40000][K]bf16 @ Bt^T + bias
// 128x128 tile, 4 waves, each wave 64x64 (4x4 frags of 16x16x32)
template <int K>
__global__ __launch_bounds__(256) void gemm_mfma_kernel(
    const unsigned short* __restrict__ A,
    const unsigned short* __restrict__ Bt,    // [512][K] bf16 (n-major)
    const float* __restrict__ bias,           // [512]
    unsigned short* __restrict__ C)
{
    __shared__ char lds[16384];
    char* ldsA = lds;
    char* ldsB = lds + 8192;
    int tid = threadIdx.x;
    int lane = tid & 63, wave = tid >> 6;
    int l16 = lane & 15, quad = lane >> 4;
    int wm = (wave >> 1) * 64, wn = (wave & 1) * 64;
    int m0 = blockIdx.x * 128;
    int n0 = blockIdx.y * 128;

    f32x4 acc[4][4] = {};

    for (int k0 = 0; k0 < K; k0 += 32) {
#pragma unroll
        for (int j = 0; j < 2; j++) {
            int o = wave * 2048 + j * 1024;
            int boff = o + lane * 16;
            int row = boff >> 6, ko = boff & 63;
            int gr = m0 + row;
            gr = gr < N_NODES ? gr : (N_NODES - 1);
            const char* gpA = (const char*)A + (size_t)gr * (K * 2) + k0 * 2 + ko;
            __builtin_amdgcn_global_load_lds(
                (const __attribute__((address_space(1))) void*)gpA,
                (__attribute__((address_space(3))) void*)(ldsA + o), 16, 0, 0);
            const char* gpB = (const char*)Bt + (size_t)(n0 + row) * (K * 2) + k0 * 2 + ko;
            __builtin_amdgcn_global_load_lds(
                (const __attribute__((address_space(1))) void*)gpB,
                (__attribute__((address_space(3))) void*)(ldsB + o), 16, 0, 0);
        }
        __syncthreads();
        bf16x8 af[4], bfr[4];
#pragma unroll
        for (int i = 0; i < 4; i++)
            af[i] = *(const bf16x8*)(ldsA + (wm + i * 16 + l16) * 64 + quad * 16);
#pragma unroll
        for (int j = 0; j < 4; j++)
            bfr[j] = *(const bf16x8*)(ldsB + (wn + j * 16 + l16) * 64 + quad * 16);
#pragma unroll
        for (int i = 0; i < 4; i++)
#pragma unroll
            for (int j = 0; j < 4; j++)
                acc[i][j] = __builtin_amdgcn_mfma_f32_16x16x32_bf16(af[i], bfr[j], acc[i][j], 0, 0, 0);
        __syncthreads();
    }

    float biasj[4];
#pragma unroll
    for (int j = 0; j < 4; j++) biasj[j] = bias[n0 + wn + j * 16 + l16];
#pragma unroll
    for (int i = 0; i < 4; i++) {
        int gr0 = m0 + wm + i * 16 + quad * 4;
#pragma unroll
        for (int j = 0; j < 4; j++) {
            int col = n0 + wn + j * 16 + l16;
#pragma unroll
            for (int rg = 0; rg < 4; rg++) {
                float a = acc[i][j][rg] + biasj[j];
                float b = __shfl_xor(a, 1);
                int grow = gr0 + rg;
                if (!(lane & 1) && grow < N_NODES) {
                    unsigned u = f2bfbits(a) | (f2bfbits(b) << 16);
                    *(unsigned*)((char*)C + ((size_t)grow * 512 + col) * 2) = u;
                }
            }
        }
    }
}

// ---------------- fused GATv2 edge stage, bf16 XLR, one wave per dst ----------
// XLR: [N][512] bf16: xl h0 ch0..127 (bytes 0..255), xl h1 (256..511),
//                     xr h0 (512..767), xr h1 (768..1023)
// lane l owns channel pair (2l, 2l+1) of each head
__global__ __launch_bounds__(256) void gat_kernel(
    const unsigned short* __restrict__ XLR,
    const int* __restrict__ head, const int* __restrict__ nxt,
    const int* __restrict__ srcs,
    const float* __restrict__ att,   // [2][128] this relation
    const float* __restrict__ bias,  // [128]
    float* __restrict__ hacc,        // [N][128]
    int accumulate)
{
    int gtid = blockIdx.x * 256 + threadIdx.x;
    int d = gtid >> 6;
    int lane = threadIdx.x & 63;
    if (d >= N_NODES) return;
    const char* base = (const char*)XLR;

    unsigned xru0 = *(const unsigned*)(base + (size_t)d * 1024 + 512 + 4 * lane);
    unsigned xru1 = *(const unsigned*)(base + (size_t)d * 1024 + 768 + 4 * lane);
    float xr00 = bflo(xru0), xr01 = bfhi(xru0);
    float xr10 = bflo(xru1), xr11 = bfhi(xru1);
    float2 a0 = *(const float2*)(att + 2 * lane);
    float2 a1 = *(const float2*)(att + 128 + 2 * lane);

    float m0 = -1e30f, m1 = -1e30f, s0 = 0.f, s1 = 0.f;
    float acc00 = 0.f, acc01 = 0.f, acc10 = 0.f, acc11 = 0.f;

    int e = head[d];
    int src = d;   // self-loop first
    while (true) {
        const char* xb = base + (size_t)src * 1024;
        unsigned u0 = *(const unsigned*)(xb + 4 * lane);
        unsigned u1 = *(const unsigned*)(xb + 256 + 4 * lane);
        float xl00 = bflo(u0), xl01 = bfhi(u0);
        float xl10 = bflo(u1), xl11 = bfhi(u1);
        float t00 = xl00 + xr00; t00 = t00 > 0.f ? t00 : NEG_SLOPE * t00;
        float t01 = xl01 + xr01; t01 = t01 > 0.f ? t01 : NEG_SLOPE * t01;
        float t10 = xl10 + xr10; t10 = t10 > 0.f ? t10 : NEG_SLOPE * t10;
        float t11 = xl11 + xr11; t11 = t11 > 0.f ? t11 : NEG_SLOPE * t11;
        float p0 = t00 * a0.x + t01 * a0.y;
        float p1 = t10 * a1.x + t11 * a1.y;
#pragma unroll
        for (int off = 32; off >= 1; off >>= 1) {
            p0 += __shfl_xor(p0, off, 64);
            p1 += __shfl_xor(p1, off, 64);
        }
        float mn = fmaxf(m0, p0);
        float sc = __expf(m0 - mn);
        float w  = __expf(p0 - mn);
        s0 = s0 * sc + w;
        acc00 = acc00 * sc + w * xl00;
        acc01 = acc01 * sc + w * xl01;
        m0 = mn;
        mn = fmaxf(m1, p1);
        sc = __expf(m1 - mn);
        w  = __expf(p1 - mn);
        s1 = s1 * sc + w;
        acc10 = acc10 * sc + w * xl10;
        acc11 = acc11 * sc + w * xl11;
        m1 = mn;

        if (e < 0) break;
        src = srcs[e];
        e = nxt[e];
    }
    float o0 = 0.5f * (acc00 / s0 + acc10 / s1) + bias[2 * lane];
    float o1 = 0.5f * (acc01 / s0 + acc11 / s1) + bias[2 * lane + 1];
    float* hp = hacc + (size_t)d * 128 + 2 * lane;
    if (accumulate) {
        float2 old = *(float2*)hp;
        old.x += o0; old.y += o1;
        *(float2*)hp = old;
    } else {
        float2 v; v.x = o0; v.y = o1;
        *(float2*)hp = v;
    }
}

// ---------------- tanh + layernorm: fp32 out (pool) + bf16 out (next GEMM) ----
__global__ __launch_bounds__(256) void tanh_ln_kernel(
    const float* __restrict__ hacc, const float* __restrict__ g,
    const float* __restrict__ b, float* __restrict__ houtf,
    unsigned* __restrict__ houtb)
{
    int gtid = blockIdx.x * 256 + threadIdx.x;
    int n = gtid >> 6;
    int lane = threadIdx.x & 63;
    if (n >= N_NODES) return;
    float2 v = *(const float2*)(hacc + (size_t)n * 128 + 2 * lane);
    float v0 = tanhf(v.x), v1 = tanhf(v.y);
    float sum = v0 + v1, sq = v0 * v0 + v1 * v1;
#pragma unroll
    for (int off = 32; off >= 1; off >>= 1) {
        sum += __shfl_xor(sum, off, 64);
        sq  += __shfl_xor(sq, off, 64);
    }
    float mean = sum * (1.f / 128.f);
    float var = sq * (1.f / 128.f) - mean * mean;
    float rstd = rsqrtf(var + 1e-5f);
    float2 gg = *(const float2*)(g + 2 * lane);
    float2 bb = *(const float2*)(b + 2 * lane);
    float o0 = (v0 - mean) * rstd * gg.x + bb.x;
    float o1 = (v1 - mean) * rstd * gg.y + bb.y;
    float2 of; of.x = o0; of.y = o1;
    *(float2*)(houtf + (size_t)n * 128 + 2 * lane) = of;
    houtb[n * 64 + lane] = f2bfbits(o0) | (f2bfbits(o1) << 16);
}

// ---------------- attention pooling: one wave per graph ----------------
__global__ __launch_bounds__(256) void pool_kernel(
    const float* __restrict__ h, const float* __restrict__ query,
    float* __restrict__ gout)
{
    int gtid = blockIdx.x * 256 + threadIdx.x;
    int bg = gtid >> 6;
    int lane = threadIdx.x & 63;
    if (bg >= B_GRAPHS) return;
    float2 q = *(const float2*)(query + 2 * lane);
    float mx = -1e30f, ssum = 0.f, g0 = 0.f, g1 = 0.f;
    for (int i = 0; i < NODES_PER_G; i++) {
        float2 hv = *(const float2*)(h + (size_t)(bg * NODES_PER_G + i) * 128 + 2 * lane);
        float p = hv.x * q.x + hv.y * q.y;
#pragma unroll
        for (int off = 32; off >= 1; off >>= 1) p += __shfl_xor(p, off, 64);
        float mn = fmaxf(mx, p);
        float sc = __expf(mx - mn), w = __expf(p - mn);
        ssum = ssum * sc + w;
        g0 = g0 * sc + w * hv.x;
        g1 = g1 * sc + w * hv.y;
        mx = mn;
    }
    float2 o; o.x = g0 / ssum; o.y = g1 / ssum;
    *(float2*)(gout + (size_t)bg * 128 + 2 * lane) = o;
}

// ---------------- final projection ----------------
__global__ __launch_bounds__(128) void proj_kernel(
    const float* __restrict__ g, const float* __restrict__ W,
    const float* __restrict__ bias, float* __restrict__ out)
{
    int bg = blockIdx.x;
    int o = threadIdx.x;
    const float* gp = g + (size_t)bg * 128;
    float acc = bias[o];
    for (int k = 0; k < 128; k++) acc = fmaf(gp[k], W[k * 128 + o], acc);
    out[(size_t)bg * 128 + o] = acc;
}

extern "C" void kernel_launch(void* const* d_in, const int* in_sizes, int n_in,
                              void* d_out, int out_size, void* d_ws, size_t ws_size,
                              hipStream_t stream)
{
    const float* x     = (const float*)d_in[0];
    const int*   ei    = (const int*)d_in[1];
    const float* Wl1   = (const float*)d_in[3];
    const float* bl1   = (const float*)d_in[4];
    const float* Wr1   = (const float*)d_in[5];
    const float* br1   = (const float*)d_in[6];
    const float* att1  = (const float*)d_in[7];
    const float* bias1 = (const float*)d_in[8];
    const float* Wl2   = (const float*)d_in[9];
    const float* bl2   = (const float*)d_in[10];
    const float* Wr2   = (const float*)d_in[11];
    const float* br2   = (const float*)d_in[12];
    const float* att2  = (const float*)d_in[13];
    const float* bias2 = (const float*)d_in[14];
    const float* ln1g  = (const float*)d_in[15];
    const float* ln1b  = (const float*)d_in[16];
    const float* ln2g  = (const float*)d_in[17];
    const float* ln2b  = (const float*)d_in[18];
    const float* query = (const float*)d_in[19];
    const float* projW = (const float*)d_in[20];
    const float* projb = (const float*)d_in[21];
    float* out = (float*)d_out;

    // workspace (all regions fully rewritten every call)
    unsigned short* xlr  = (unsigned short*)d_ws;               // 40000*512 bf16 = 40.96 MB
    float*  hacc = (float*)(xlr + (size_t)N_NODES * 512);       // 20.48 MB
    float*  h1f  = hacc + (size_t)N_NODES * 128;                // 20.48 MB
    unsigned short* h1bf = (unsigned short*)(h1f + (size_t)N_NODES * 128); // 10.24 MB
    unsigned short* xbf  = h1bf + (size_t)N_NODES * 128;        // 2.56 MB
    unsigned short* Bt1  = xbf + (size_t)N_NODES * 32;          // 6*512*32  = 0.20 MB
    unsigned short* Bt2  = Bt1 + R_REL * 512 * 32;              // 6*512*128 = 0.79 MB
    float* bc1  = (float*)(Bt2 + R_REL * 512 * 128);            // 6*512 f32
    float* bc2  = bc1 + R_REL * 512;
    int* headp  = (int*)(bc2 + R_REL * 512);                    // R*N
    int* nextp  = headp + R_REL * N_NODES;                      // R*E
    float* gb   = (float*)xlr;                                  // alias after GATs done

    hipMemsetAsync(headp, 0xFF, sizeof(int) * R_REL * N_NODES, stream);
    build_links_kernel<<<(R_REL * E_EDGES + 255) / 256, 256, 0, stream>>>(ei, headp, nextp);
    cvt_bf16_kernel<<<(N_NODES * 32 / 2 + 255) / 256, 256, 0, stream>>>(x, (unsigned*)xbf, N_NODES * 16);
    prep_w_kernel<<<(R_REL * 512 * 32 + 255) / 256, 256, 0, stream>>>(Wl1, Wr1, bl1, br1, Bt1, bc1, 32);
    prep_w_kernel<<<(R_REL * 512 * 128 + 255) / 256, 256, 0, stream>>>(Wl2, Wr2, bl2, br2, Bt2, bc2, 128);

    dim3 ggrid((N_NODES + 127) / 128, 4);
    // ---- layer 1 ----
    for (int r = 0; r < R_REL; r++) {
        gemm_mfma_kernel<32><<<ggrid, 256, 0, stream>>>(
            xbf, Bt1 + (size_t)r * 512 * 32, bc1 + r * 512, xlr);
        gat_kernel<<<N_NODES / 4, 256, 0, stream>>>(
            xlr, headp + r * N_NODES, nextp + (size_t)r * E_EDGES,
            ei + (size_t)r * 2 * E_EDGES, att1 + r * 256, bias1 + r * 128, hacc, r > 0);
    }
    tanh_ln_kernel<<<N_NODES / 4, 256, 0, stream>>>(hacc, ln1g, ln1b, h1f, (unsigned*)h1bf);
    // ---- layer 2 ----
    for (int r = 0; r < R_REL; r++) {
        gemm_mfma_kernel<128><<<ggrid, 256, 0, stream>>>(
            h1bf, Bt2 + (size_t)r * 512 * 128, bc2 + r * 512, xlr);
        gat_kernel<<<N_NODES / 4, 256, 0, stream>>>(
            xlr, headp + r * N_NODES, nextp + (size_t)r * E_EDGES,
            ei + (size_t)r * 2 * E_EDGES, att2 + r * 256, bias2 + r * 128, hacc, r > 0);
    }
    tanh_ln_kernel<<<N_NODES / 4, 256, 0, stream>>>(hacc, ln2g, ln2b, h1f, (unsigned*)h1bf);
    // ---- pooling + projection ----
    pool_kernel<<<B_GRAPHS / 4, 256, 0, stream>>>(h1f, query, gb);
    proj_kernel<<<B_GRAPHS, 128, 0, stream>>>(gb, projW, projb, out);
}

// Round 3
// 525.984 us; speedup vs baseline: 2.1832x; 1.3227x over previous
//
#include <hip/hip_runtime.h>
#include <math.h>

#define N_NODES 40000
#define E_EDGES 60000
#define R_REL 6
#define IN_F 32
#define HID_F 128
#define B_GRAPHS 2000
#define NODES_PER_G 20
#define NEG_SLOPE 0.2f

typedef __bf16 bf16x8 __attribute__((ext_vector_type(8)));
typedef float f32x4 __attribute__((ext_vector_type(4)));

__device__ __forceinline__ unsigned f2bfbits(float f) {
    unsigned u = __builtin_bit_cast(unsigned, f);
    return (u + 0x7FFFu + ((u >> 16) & 1u)) >> 16;   // RNE
}
__device__ __forceinline__ float bflo(unsigned u) { return __builtin_bit_cast(float, u << 16); }
__device__ __forceinline__ float bfhi(unsigned u) { return __builtin_bit_cast(float, u & 0xFFFF0000u); }

// ---------------- adjacency: linked-list by dst ----------------
__global__ __launch_bounds__(256) void build_links_kernel(
    const int* __restrict__ ei, int* __restrict__ head, int* __restrict__ nxt)
{
    int idx = blockIdx.x * 256 + threadIdx.x;
    if (idx >= R_REL * E_EDGES) return;
    int r = idx / E_EDGES;
    int e = idx - r * E_EDGES;
    int dst = ei[(size_t)r * 2 * E_EDGES + E_EDGES + e];
    int old = atomicExch(&head[r * N_NODES + dst], e);
    nxt[(size_t)r * E_EDGES + e] = old;
}

// ---------------- prep: fp32 -> bf16 pairwise ----------------
__global__ __launch_bounds__(256) void cvt_bf16_kernel(
    const float* __restrict__ src, unsigned* __restrict__ dst, int npairs)
{
    int i = blockIdx.x * 256 + threadIdx.x;
    if (i >= npairs) return;
    float2 v = *(const float2*)(src + 2 * i);
    dst[i] = f2bfbits(v.x) | (f2bfbits(v.y) << 16);
}

// ---------------- prep: W[r][k][256] (l|r) -> Bt[r][512][K] bf16, bias cat ----
__global__ __launch_bounds__(256) void prep_w_kernel(
    const float* __restrict__ Wl, const float* __restrict__ Wr,
    const float* __restrict__ bl, const float* __restrict__ br,
    unsigned short* __restrict__ Bt, float* __restrict__ bcat, int K)
{
    int idx = blockIdx.x * 256 + threadIdx.x;
    if (idx >= R_REL * 512 * K) return;
    int k = idx % K;
    int rn = idx / K;
    int n = rn % 512;
    int r = rn / 512;
    int nn = n & 255;
    const float* W = (n < 256) ? Wl : Wr;
    float w = W[((size_t)r * K + k) * 256 + nn];
    Bt[idx] = (unsigned short)f2bfbits(w);
    if (k == 0)
        bcat[rn] = (n < 256) ? bl[r * 256 + nn] : br[r * 256 + nn];
}

// ---------------- MFMA GEMM over all 6 relations (blockIdx.z = relation) ------
// C[z][40000][512]bf16 = A[40000][K]bf16 @ Bt[z]^T + bias[z]
template <int K>
__global__ __launch_bounds__(256) void gemm_mfma_kernel(
    const unsigned short* __restrict__ A,
    const unsigned short* __restrict__ BtAll,   // [R][512][K] bf16 (n-major)
    const float* __restrict__ biasAll,          // [R][512]
    unsigned short* __restrict__ CAll)          // [R][40000][512]
{
    __shared__ char lds[16384];
    char* ldsA = lds;
    char* ldsB = lds + 8192;
    const unsigned short* Bt = BtAll + (size_t)blockIdx.z * 512 * K;
    const float* bias = biasAll + blockIdx.z * 512;
    unsigned short* C = CAll + (size_t)blockIdx.z * N_NODES * 512;
    int tid = threadIdx.x;
    int lane = tid & 63, wave = tid >> 6;
    int l16 = lane & 15, quad = lane >> 4;
    int wm = (wave >> 1) * 64, wn = (wave & 1) * 64;
    int m0 = blockIdx.x * 128;
    int n0 = blockIdx.y * 128;

    f32x4 acc[4][4] = {};

    for (int k0 = 0; k0 < K; k0 += 32) {
#pragma unroll
        for (int j = 0; j < 2; j++) {
            int o = wave * 2048 + j * 1024;
            int boff = o + lane * 16;
            int row = boff >> 6, ko = boff & 63;
            int gr = m0 + row;
            gr = gr < N_NODES ? gr : (N_NODES - 1);
            const char* gpA = (const char*)A + (size_t)gr * (K * 2) + k0 * 2 + ko;
            __builtin_amdgcn_global_load_lds(
                (const __attribute__((address_space(1))) void*)gpA,
                (__attribute__((address_space(3))) void*)(ldsA + o), 16, 0, 0);
            const char* gpB = (const char*)Bt + (size_t)(n0 + row) * (K * 2) + k0 * 2 + ko;
            __builtin_amdgcn_global_load_lds(
                (const __attribute__((address_space(1))) void*)gpB,
                (__attribute__((address_space(3))) void*)(ldsB + o), 16, 0, 0);
        }
        __syncthreads();
        bf16x8 af[4], bfr[4];
#pragma unroll
        for (int i = 0; i < 4; i++)
            af[i] = *(const bf16x8*)(ldsA + (wm + i * 16 + l16) * 64 + quad * 16);
#pragma unroll
        for (int j = 0; j < 4; j++)
            bfr[j] = *(const bf16x8*)(ldsB + (wn + j * 16 + l16) * 64 + quad * 16);
#pragma unroll
        for (int i = 0; i < 4; i++)
#pragma unroll
            for (int j = 0; j < 4; j++)
                acc[i][j] = __builtin_amdgcn_mfma_f32_16x16x32_bf16(af[i], bfr[j], acc[i][j], 0, 0, 0);
        __syncthreads();
    }

    float biasj[4];
#pragma unroll
    for (int j = 0; j < 4; j++) biasj[j] = bias[n0 + wn + j * 16 + l16];
#pragma unroll
    for (int i = 0; i < 4; i++) {
        int gr0 = m0 + wm + i * 16 + quad * 4;
#pragma unroll
        for (int j = 0; j < 4; j++) {
            int col = n0 + wn + j * 16 + l16;
#pragma unroll
            for (int rg = 0; rg < 4; rg++) {
                float a = acc[i][j][rg] + biasj[j];
                float b = __shfl_xor(a, 1);
                int grow = gr0 + rg;
                if (!(lane & 1) && grow < N_NODES) {
                    unsigned u = f2bfbits(a) | (f2bfbits(b) << 16);
                    *(unsigned*)((char*)C + ((size_t)grow * 512 + col) * 2) = u;
                }
            }
        }
    }
}

// ------- fused 6-relation GATv2 + relation-sum + tanh + LayerNorm -------------
// XLR: [R][N][512] bf16: [0:256)=xl (h*128+c), [256:512)=xr
// one wave per dst; lane l owns channel pair (2l, 2l+1) of each head
__global__ __launch_bounds__(256) void gat6_ln_kernel(
    const unsigned short* __restrict__ XLR,
    const int* __restrict__ head,     // [R][N]
    const int* __restrict__ nxt,      // [R][E]
    const int* __restrict__ ei,       // [R][2][E]
    const float* __restrict__ att,    // [R][2][128]
    const float* __restrict__ bias,   // [R][128]
    const float* __restrict__ lng, const float* __restrict__ lnb,
    unsigned* __restrict__ hout)      // [N][64] packed bf16 pairs
{
    int gtid = blockIdx.x * 256 + threadIdx.x;
    int d = gtid >> 6;
    int lane = threadIdx.x & 63;
    if (d >= N_NODES) return;

    float tot0 = 0.f, tot1 = 0.f;
#pragma unroll 1
    for (int r = 0; r < R_REL; r++) {
        const char* base = (const char*)XLR + (size_t)r * N_NODES * 1024;
        unsigned xru0 = *(const unsigned*)(base + (size_t)d * 1024 + 512 + 4 * lane);
        unsigned xru1 = *(const unsigned*)(base + (size_t)d * 1024 + 768 + 4 * lane);
        float xr00 = bflo(xru0), xr01 = bfhi(xru0);
        float xr10 = bflo(xru1), xr11 = bfhi(xru1);
        float2 a0 = *(const float2*)(att + r * 256 + 2 * lane);
        float2 a1 = *(const float2*)(att + r * 256 + 128 + 2 * lane);
        const int* srcs = ei + (size_t)r * 2 * E_EDGES;
        const int* nx = nxt + (size_t)r * E_EDGES;

        float m0 = -1e30f, m1 = -1e30f, s0 = 0.f, s1 = 0.f;
        float acc00 = 0.f, acc01 = 0.f, acc10 = 0.f, acc11 = 0.f;

        int e = head[r * N_NODES + d];
        int src = d;    // self-loop first
        while (true) {
            const char* xb = base + (size_t)src * 1024;
            unsigned u0 = *(const unsigned*)(xb + 4 * lane);
            unsigned u1 = *(const unsigned*)(xb + 256 + 4 * lane);
            float xl00 = bflo(u0), xl01 = bfhi(u0);
            float xl10 = bflo(u1), xl11 = bfhi(u1);
            float t00 = xl00 + xr00; t00 = t00 > 0.f ? t00 : NEG_SLOPE * t00;
            float t01 = xl01 + xr01; t01 = t01 > 0.f ? t01 : NEG_SLOPE * t01;
            float t10 = xl10 + xr10; t10 = t10 > 0.f ? t10 : NEG_SLOPE * t10;
            float t11 = xl11 + xr11; t11 = t11 > 0.f ? t11 : NEG_SLOPE * t11;
            float p0 = t00 * a0.x + t01 * a0.y;
            float p1 = t10 * a1.x + t11 * a1.y;
#pragma unroll
            for (int off = 32; off >= 1; off >>= 1) {
                p0 += __shfl_xor(p0, off, 64);
                p1 += __shfl_xor(p1, off, 64);
            }
            float mn = fmaxf(m0, p0);
            float sc = __expf(m0 - mn);
            float w  = __expf(p0 - mn);
            s0 = s0 * sc + w;
            acc00 = acc00 * sc + w * xl00;
            acc01 = acc01 * sc + w * xl01;
            m0 = mn;
            mn = fmaxf(m1, p1);
            sc = __expf(m1 - mn);
            w  = __expf(p1 - mn);
            s1 = s1 * sc + w;
            acc10 = acc10 * sc + w * xl10;
            acc11 = acc11 * sc + w * xl11;
            m1 = mn;

            if (e < 0) break;
            src = srcs[e];
            e = nx[e];
        }
        tot0 += 0.5f * (acc00 / s0 + acc10 / s1) + bias[r * 128 + 2 * lane];
        tot1 += 0.5f * (acc01 / s0 + acc11 / s1) + bias[r * 128 + 2 * lane + 1];
    }
    // tanh + layernorm (wave-wide over 128 channels)
    float v0 = tanhf(tot0), v1 = tanhf(tot1);
    float sum = v0 + v1, sq = v0 * v0 + v1 * v1;
#pragma unroll
    for (int off = 32; off >= 1; off >>= 1) {
        sum += __shfl_xor(sum, off, 64);
        sq  += __shfl_xor(sq, off, 64);
    }
    float mean = sum * (1.f / 128.f);
    float var = sq * (1.f / 128.f) - mean * mean;
    float rstd = rsqrtf(var + 1e-5f);
    float2 gg = *(const float2*)(lng + 2 * lane);
    float2 bb = *(const float2*)(lnb + 2 * lane);
    float o0 = (v0 - mean) * rstd * gg.x + bb.x;
    float o1 = (v1 - mean) * rstd * gg.y + bb.y;
    hout[d * 64 + lane] = f2bfbits(o0) | (f2bfbits(o1) << 16);
}

// ---------------- attention pooling over bf16 h: one wave per graph -----------
__global__ __launch_bounds__(256) void pool_kernel(
    const unsigned* __restrict__ hb, const float* __restrict__ query,
    float* __restrict__ gout)
{
    int gtid = blockIdx.x * 256 + threadIdx.x;
    int bg = gtid >> 6;
    int lane = threadIdx.x & 63;
    if (bg >= B_GRAPHS) return;
    float2 q = *(const float2*)(query + 2 * lane);
    float mx = -1e30f, ssum = 0.f, g0 = 0.f, g1 = 0.f;
    for (int i = 0; i < NODES_PER_G; i++) {
        unsigned u = hb[(size_t)(bg * NODES_PER_G + i) * 64 + lane];
        float h0 = bflo(u), h1 = bfhi(u);
        float p = h0 * q.x + h1 * q.y;
#pragma unroll
        for (int off = 32; off >= 1; off >>= 1) p += __shfl_xor(p, off, 64);
        float mn = fmaxf(mx, p);
        float sc = __expf(mx - mn), w = __expf(p - mn);
        ssum = ssum * sc + w;
        g0 = g0 * sc + w * h0;
        g1 = g1 * sc + w * h1;
        mx = mn;
    }
    float2 o; o.x = g0 / ssum; o.y = g1 / ssum;
    *(float2*)(gout + (size_t)bg * 128 + 2 * lane) = o;
}

// ---------------- final projection ----------------
__global__ __launch_bounds__(128) void proj_kernel(
    const float* __restrict__ g, const float* __restrict__ W,
    const float* __restrict__ bias, float* __restrict__ out)
{
    int bg = blockIdx.x;
    int o = threadIdx.x;
    const float* gp = g + (size_t)bg * 128;
    float acc = bias[o];
    for (int k = 0; k < 128; k++) acc = fmaf(gp[k], W[k * 128 + o], acc);
    out[(size_t)bg * 128 + o] = acc;
}

extern "C" void kernel_launch(void* const* d_in, const int* in_sizes, int n_in,
                              void* d_out, int out_size, void* d_ws, size_t ws_size,
                              hipStream_t stream)
{
    const float* x     = (const float*)d_in[0];
    const int*   ei    = (const int*)d_in[1];
    const float* Wl1   = (const float*)d_in[3];
    const float* bl1   = (const float*)d_in[4];
    const float* Wr1   = (const float*)d_in[5];
    const float* br1   = (const float*)d_in[6];
    const float* att1  = (const float*)d_in[7];
    const float* bias1 = (const float*)d_in[8];
    const float* Wl2   = (const float*)d_in[9];
    const float* bl2   = (const float*)d_in[10];
    const float* Wr2   = (const float*)d_in[11];
    const float* br2   = (const float*)d_in[12];
    const float* att2  = (const float*)d_in[13];
    const float* bias2 = (const float*)d_in[14];
    const float* ln1g  = (const float*)d_in[15];
    const float* ln1b  = (const float*)d_in[16];
    const float* ln2g  = (const float*)d_in[17];
    const float* ln2b  = (const float*)d_in[18];
    const float* query = (const float*)d_in[19];
    const float* projW = (const float*)d_in[20];
    const float* projb = (const float*)d_in[21];
    float* out = (float*)d_out;

    // workspace layout — 262,991,616 B total (< 256 MiB), all rewritten per call
    unsigned short* xlr6 = (unsigned short*)d_ws;                 // 6*40000*512 bf16 = 245.76 MB
    unsigned short* h1bf = xlr6 + (size_t)R_REL * N_NODES * 512;  // 40000*128 bf16 = 10.24 MB
    unsigned short* xbf  = h1bf + (size_t)N_NODES * 128;          // 40000*32 bf16 = 2.56 MB
    unsigned short* Bt1  = xbf + (size_t)N_NODES * 32;            // 6*512*32 bf16
    unsigned short* Bt2  = Bt1 + R_REL * 512 * 32;                // 6*512*128 bf16
    float* bc1  = (float*)(Bt2 + R_REL * 512 * 128);              // 6*512 f32
    float* bc2  = bc1 + R_REL * 512;                              // 6*512 f32
    float* gb   = bc2 + R_REL * 512;                              // 2000*128 f32
    int* headp  = (int*)(gb + (size_t)B_GRAPHS * 128);            // 6*40000
    int* nextp  = headp + R_REL * N_NODES;                        // 6*60000

    hipMemsetAsync(headp, 0xFF, sizeof(int) * R_REL * N_NODES, stream);
    build_links_kernel<<<(R_REL * E_EDGES + 255) / 256, 256, 0, stream>>>(ei, headp, nextp);
    cvt_bf16_kernel<<<(N_NODES * 16 + 255) / 256, 256, 0, stream>>>(x, (unsigned*)xbf, N_NODES * 16);
    prep_w_kernel<<<(R_REL * 512 * 32 + 255) / 256, 256, 0, stream>>>(Wl1, Wr1, bl1, br1, Bt1, bc1, 32);
    prep_w_kernel<<<(R_REL * 512 * 128 + 255) / 256, 256, 0, stream>>>(Wl2, Wr2, bl2, br2, Bt2, bc2, 128);

    dim3 ggrid((N_NODES + 127) / 128, 4, R_REL);
    // ---- layer 1 ----
    gemm_mfma_kernel<32><<<ggrid, 256, 0, stream>>>(xbf, Bt1, bc1, xlr6);
    gat6_ln_kernel<<<N_NODES / 4, 256, 0, stream>>>(
        xlr6, headp, nextp, ei, att1, bias1, ln1g, ln1b, (unsigned*)h1bf);
    // ---- layer 2 ----
    gemm_mfma_kernel<128><<<ggrid, 256, 0, stream>>>(h1bf, Bt2, bc2, xlr6);
    gat6_ln_kernel<<<N_NODES / 4, 256, 0, stream>>>(
        xlr6, headp, nextp, ei, att2, bias2, ln2g, ln2b, (unsigned*)h1bf);
    // ---- pooling + projection ----
    pool_kernel<<<B_GRAPHS / 4, 256, 0, stream>>>((unsigned*)h1bf, query, gb);
    proj_kernel<<<B_GRAPHS, 128, 0, stream>>>(gb, projW, projb, out);
}

// Round 4
// 497.627 us; speedup vs baseline: 2.3076x; 1.0570x over previous
//
#include <hip/hip_runtime.h>
#include <math.h>

#define N_NODES 40000
#define E_EDGES 60000
#define R_REL 6
#define IN_F 32
#define HID_F 128
#define B_GRAPHS 2000
#define NODES_PER_G 20
#define NEG_SLOPE 0.2f

typedef __bf16 bf16x8 __attribute__((ext_vector_type(8)));
typedef float f32x4 __attribute__((ext_vector_type(4)));

__device__ __forceinline__ unsigned f2bfbits(float f) {
    unsigned u = __builtin_bit_cast(unsigned, f);
    return (u + 0x7FFFu + ((u >> 16) & 1u)) >> 16;   // RNE
}
__device__ __forceinline__ float bflo(unsigned u) { return __builtin_bit_cast(float, u << 16); }
__device__ __forceinline__ float bfhi(unsigned u) { return __builtin_bit_cast(float, u & 0xFFFF0000u); }

// ---------------- adjacency: linked-list by dst ----------------
__global__ __launch_bounds__(256) void build_links_kernel(
    const int* __restrict__ ei, int* __restrict__ head, int* __restrict__ nxt)
{
    int idx = blockIdx.x * 256 + threadIdx.x;
    if (idx >= R_REL * E_EDGES) return;
    int r = idx / E_EDGES;
    int e = idx - r * E_EDGES;
    int dst = ei[(size_t)r * 2 * E_EDGES + E_EDGES + e];
    int old = atomicExch(&head[r * N_NODES + dst], e);
    nxt[(size_t)r * E_EDGES + e] = old;
}

// ---------------- prep: fp32 -> bf16 pairwise ----------------
__global__ __launch_bounds__(256) void cvt_bf16_kernel(
    const float* __restrict__ src, unsigned* __restrict__ dst, int npairs)
{
    int i = blockIdx.x * 256 + threadIdx.x;
    if (i >= npairs) return;
    float2 v = *(const float2*)(src + 2 * i);
    dst[i] = f2bfbits(v.x) | (f2bfbits(v.y) << 16);
}

// ---------------- prep: W[r][k][256] (l|r) -> Bt[r][512][K] bf16, bias cat ----
__global__ __launch_bounds__(256) void prep_w_kernel(
    const float* __restrict__ Wl, const float* __restrict__ Wr,
    const float* __restrict__ bl, const float* __restrict__ br,
    unsigned short* __restrict__ Bt, float* __restrict__ bcat, int K)
{
    int idx = blockIdx.x * 256 + threadIdx.x;
    if (idx >= R_REL * 512 * K) return;
    int k = idx % K;
    int rn = idx / K;
    int n = rn % 512;
    int r = rn / 512;
    int nn = n & 255;
    const float* W = (n < 256) ? Wl : Wr;
    float w = W[((size_t)r * K + k) * 256 + nn];
    Bt[idx] = (unsigned short)f2bfbits(w);
    if (k == 0)
        bcat[rn] = (n < 256) ? bl[r * 256 + nn] : br[r * 256 + nn];
}

// ---------------- MFMA GEMM over all 6 relations (blockIdx.z = relation) ------
template <int K>
__global__ __launch_bounds__(256) void gemm_mfma_kernel(
    const unsigned short* __restrict__ A,
    const unsigned short* __restrict__ BtAll,   // [R][512][K] bf16 (n-major)
    const float* __restrict__ biasAll,          // [R][512]
    unsigned short* __restrict__ CAll)          // [R][40000][512]
{
    __shared__ char lds[16384];
    char* ldsA = lds;
    char* ldsB = lds + 8192;
    const unsigned short* Bt = BtAll + (size_t)blockIdx.z * 512 * K;
    const float* bias = biasAll + blockIdx.z * 512;
    unsigned short* C = CAll + (size_t)blockIdx.z * N_NODES * 512;
    int tid = threadIdx.x;
    int lane = tid & 63, wave = tid >> 6;
    int l16 = lane & 15, quad = lane >> 4;
    int wm = (wave >> 1) * 64, wn = (wave & 1) * 64;
    int m0 = blockIdx.x * 128;
    int n0 = blockIdx.y * 128;

    f32x4 acc[4][4] = {};

    for (int k0 = 0; k0 < K; k0 += 32) {
#pragma unroll
        for (int j = 0; j < 2; j++) {
            int o = wave * 2048 + j * 1024;
            int boff = o + lane * 16;
            int row = boff >> 6, ko = boff & 63;
            int gr = m0 + row;
            gr = gr < N_NODES ? gr : (N_NODES - 1);
            const char* gpA = (const char*)A + (size_t)gr * (K * 2) + k0 * 2 + ko;
            __builtin_amdgcn_global_load_lds(
                (const __attribute__((address_space(1))) void*)gpA,
                (__attribute__((address_space(3))) void*)(ldsA + o), 16, 0, 0);
            const char* gpB = (const char*)Bt + (size_t)(n0 + row) * (K * 2) + k0 * 2 + ko;
            __builtin_amdgcn_global_load_lds(
                (const __attribute__((address_space(1))) void*)gpB,
                (__attribute__((address_space(3))) void*)(ldsB + o), 16, 0, 0);
        }
        __syncthreads();
        bf16x8 af[4], bfr[4];
#pragma unroll
        for (int i = 0; i < 4; i++)
            af[i] = *(const bf16x8*)(ldsA + (wm + i * 16 + l16) * 64 + quad * 16);
#pragma unroll
        for (int j = 0; j < 4; j++)
            bfr[j] = *(const bf16x8*)(ldsB + (wn + j * 16 + l16) * 64 + quad * 16);
#pragma unroll
        for (int i = 0; i < 4; i++)
#pragma unroll
            for (int j = 0; j < 4; j++)
                acc[i][j] = __builtin_amdgcn_mfma_f32_16x16x32_bf16(af[i], bfr[j], acc[i][j], 0, 0, 0);
        __syncthreads();
    }

    float biasj[4];
#pragma unroll
    for (int j = 0; j < 4; j++) biasj[j] = bias[n0 + wn + j * 16 + l16];
#pragma unroll
    for (int i = 0; i < 4; i++) {
        int gr0 = m0 + wm + i * 16 + quad * 4;
#pragma unroll
        for (int j = 0; j < 4; j++) {
            int col = n0 + wn + j * 16 + l16;
#pragma unroll
            for (int rg = 0; rg < 4; rg++) {
                float a = acc[i][j][rg] + biasj[j];
                float b = __shfl_xor(a, 1);
                int grow = gr0 + rg;
                if (!(lane & 1) && grow < N_NODES) {
                    unsigned u = f2bfbits(a) | (f2bfbits(b) << 16);
                    *(unsigned*)((char*)C + ((size_t)grow * 512 + col) * 2) = u;
                }
            }
        }
    }
}

// ------- fused 6-relation GATv2 + relation-sum + tanh + LayerNorm -------------
// XLR row (512 bf16 = 1024 B): [0:256)B = xl head0, [256:512)B = xl head1,
//                              [512:768)B = xr head0, [768:1024)B = xr head1
// lanes 0-31 own head0 (4 ch each), lanes 32-63 own head1.
// Softmax without max-subtraction (logits tiny; clamped at 60 for safety).
__global__ __launch_bounds__(256) void gat6_ln_kernel(
    const unsigned short* __restrict__ XLR,
    const int* __restrict__ head,     // [R][N]
    const int* __restrict__ nxt,      // [R][E]
    const int* __restrict__ ei,       // [R][2][E]
    const float* __restrict__ att,    // [R][2][128]
    const float* __restrict__ bias,   // [R][128]
    const float* __restrict__ lng, const float* __restrict__ lnb,
    unsigned* __restrict__ hout)      // [N][64] packed bf16 pairs
{
    int gtid = blockIdx.x * 256 + threadIdx.x;
    int d = gtid >> 6;
    int lane = threadIdx.x & 63;
    if (d >= N_NODES) return;
    int hl = lane & 31;              // position within half (channel group)

    float tot0 = 0.f, tot1 = 0.f, tot2 = 0.f, tot3 = 0.f;
#pragma unroll 1
    for (int r = 0; r < R_REL; r++) {
        const char* base = (const char*)XLR + (size_t)r * N_NODES * 1024;
        const unsigned* xrp = (const unsigned*)(base + (size_t)d * 1024 + 512 + lane * 8);
        unsigned xu0 = xrp[0], xu1 = xrp[1];
        float xr0 = bflo(xu0), xr1 = bfhi(xu0), xr2 = bflo(xu1), xr3 = bfhi(xu1);
        // att[r][h][c]: flat r*256 + lane*4 covers both halves correctly
        float4 av = *(const float4*)(att + r * 256 + lane * 4);

        float s = 0.f, a0 = 0.f, a1 = 0.f, a2 = 0.f, a3 = 0.f;
        const int* srcs = ei + (size_t)r * 2 * E_EDGES;
        const int* nx = nxt + (size_t)r * E_EDGES;
        int e = head[r * N_NODES + d];
        int src = d;                 // self-loop first
        while (true) {
            const unsigned* xlp = (const unsigned*)(base + (size_t)src * 1024 + lane * 8);
            unsigned u0 = xlp[0], u1 = xlp[1];
            float xl0 = bflo(u0), xl1 = bfhi(u0), xl2 = bflo(u1), xl3 = bfhi(u1);
            float t0 = xl0 + xr0, t1 = xl1 + xr1, t2 = xl2 + xr2, t3 = xl3 + xr3;
            t0 = fmaxf(t0, NEG_SLOPE * t0);
            t1 = fmaxf(t1, NEG_SLOPE * t1);
            t2 = fmaxf(t2, NEG_SLOPE * t2);
            t3 = fmaxf(t3, NEG_SLOPE * t3);
            float p = t0 * av.x + t1 * av.y + t2 * av.z + t3 * av.w;
            p += __shfl_xor(p, 16);
            p += __shfl_xor(p, 8);
            p += __shfl_xor(p, 4);
            p += __shfl_xor(p, 2);
            p += __shfl_xor(p, 1);
            float w = __expf(fminf(p, 60.f));
            s += w;
            a0 = fmaf(w, xl0, a0);
            a1 = fmaf(w, xl1, a1);
            a2 = fmaf(w, xl2, a2);
            a3 = fmaf(w, xl3, a3);
            if (e < 0) break;
            src = srcs[e];
            e = nx[e];
        }
        float rs = 0.5f * __builtin_amdgcn_rcpf(s);   // fold head-mean 0.5
        float o0 = a0 * rs, o1 = a1 * rs, o2 = a2 * rs, o3 = a3 * rs;
        o0 += __shfl_xor(o0, 32);
        o1 += __shfl_xor(o1, 32);
        o2 += __shfl_xor(o2, 32);
        o3 += __shfl_xor(o3, 32);
        float4 bv = *(const float4*)(bias + r * 128 + hl * 4);
        tot0 += o0 + bv.x;
        tot1 += o1 + bv.y;
        tot2 += o2 + bv.z;
        tot3 += o3 + bv.w;
    }
    // tanh + layernorm (128 ch live in each 32-lane half, identical halves)
    float v0 = tanhf(tot0), v1 = tanhf(tot1), v2 = tanhf(tot2), v3 = tanhf(tot3);
    float sum = v0 + v1 + v2 + v3;
    float sq = v0 * v0 + v1 * v1 + v2 * v2 + v3 * v3;
#pragma unroll
    for (int off = 16; off >= 1; off >>= 1) {
        sum += __shfl_xor(sum, off);
        sq  += __shfl_xor(sq, off);
    }
    float mean = sum * (1.f / 128.f);
    float var = sq * (1.f / 128.f) - mean * mean;
    float rstd = rsqrtf(var + 1e-5f);
    float4 gg = *(const float4*)(lng + hl * 4);
    float4 bb = *(const float4*)(lnb + hl * 4);
    float o0 = (v0 - mean) * rstd * gg.x + bb.x;
    float o1 = (v1 - mean) * rstd * gg.y + bb.y;
    float o2 = (v2 - mean) * rstd * gg.z + bb.z;
    float o3 = (v3 - mean) * rstd * gg.w + bb.w;
    if (lane < 32) {
        uint2 q;
        q.x = f2bfbits(o0) | (f2bfbits(o1) << 16);
        q.y = f2bfbits(o2) | (f2bfbits(o3) << 16);
        *((uint2*)(hout + (size_t)d * 64) + hl) = q;
    }
}

// ---------------- attention pooling over bf16 h: one wave per graph -----------
__global__ __launch_bounds__(256) void pool_kernel(
    const unsigned* __restrict__ hb, const float* __restrict__ query,
    float* __restrict__ gout)
{
    int gtid = blockIdx.x * 256 + threadIdx.x;
    int bg = gtid >> 6;
    int lane = threadIdx.x & 63;
    if (bg >= B_GRAPHS) return;
    float2 q = *(const float2*)(query + 2 * lane);
    float mx = -1e30f, ssum = 0.f, g0 = 0.f, g1 = 0.f;
    for (int i = 0; i < NODES_PER_G; i++) {
        unsigned u = hb[(size_t)(bg * NODES_PER_G + i) * 64 + lane];
        float h0 = bflo(u), h1 = bfhi(u);
        float p = h0 * q.x + h1 * q.y;
#pragma unroll
        for (int off = 32; off >= 1; off >>= 1) p += __shfl_xor(p, off, 64);
        float mn = fmaxf(mx, p);
        float sc = __expf(mx - mn), w = __expf(p - mn);
        ssum = ssum * sc + w;
        g0 = g0 * sc + w * h0;
        g1 = g1 * sc + w * h1;
        mx = mn;
    }
    float2 o; o.x = g0 / ssum; o.y = g1 / ssum;
    *(float2*)(gout + (size_t)bg * 128 + 2 * lane) = o;
}

// ---------------- final projection ----------------
__global__ __launch_bounds__(128) void proj_kernel(
    const float* __restrict__ g, const float* __restrict__ W,
    const float* __restrict__ bias, float* __restrict__ out)
{
    int bg = blockIdx.x;
    int o = threadIdx.x;
    const float* gp = g + (size_t)bg * 128;
    float acc = bias[o];
    for (int k = 0; k < 128; k++) acc = fmaf(gp[k], W[k * 128 + o], acc);
    out[(size_t)bg * 128 + o] = acc;
}

extern "C" void kernel_launch(void* const* d_in, const int* in_sizes, int n_in,
                              void* d_out, int out_size, void* d_ws, size_t ws_size,
                              hipStream_t stream)
{
    const float* x     = (const float*)d_in[0];
    const int*   ei    = (const int*)d_in[1];
    const float* Wl1   = (const float*)d_in[3];
    const float* bl1   = (const float*)d_in[4];
    const float* Wr1   = (const float*)d_in[5];
    const float* br1   = (const float*)d_in[6];
    const float* att1  = (const float*)d_in[7];
    const float* bias1 = (const float*)d_in[8];
    const float* Wl2   = (const float*)d_in[9];
    const float* bl2   = (const float*)d_in[10];
    const float* Wr2   = (const float*)d_in[11];
    const float* br2   = (const float*)d_in[12];
    const float* att2  = (const float*)d_in[13];
    const float* bias2 = (const float*)d_in[14];
    const float* ln1g  = (const float*)d_in[15];
    const float* ln1b  = (const float*)d_in[16];
    const float* ln2g  = (const float*)d_in[17];
    const float* ln2b  = (const float*)d_in[18];
    const float* query = (const float*)d_in[19];
    const float* projW = (const float*)d_in[20];
    const float* projb = (const float*)d_in[21];
    float* out = (float*)d_out;

    // workspace layout — all regions rewritten every call
    unsigned short* xlr6 = (unsigned short*)d_ws;                 // 6*40000*512 bf16 = 245.76 MB
    unsigned short* h1bf = xlr6 + (size_t)R_REL * N_NODES * 512;  // 10.24 MB
    unsigned short* xbf  = h1bf + (size_t)N_NODES * 128;          // 2.56 MB
    unsigned short* Bt1  = xbf + (size_t)N_NODES * 32;
    unsigned short* Bt2  = Bt1 + R_REL * 512 * 32;
    float* bc1  = (float*)(Bt2 + R_REL * 512 * 128);
    float* bc2  = bc1 + R_REL * 512;
    float* gb   = bc2 + R_REL * 512;                              // 2000*128 f32
    int* headp  = (int*)(gb + (size_t)B_GRAPHS * 128);
    int* nextp  = headp + R_REL * N_NODES;

    hipMemsetAsync(headp, 0xFF, sizeof(int) * R_REL * N_NODES, stream);
    build_links_kernel<<<(R_REL * E_EDGES + 255) / 256, 256, 0, stream>>>(ei, headp, nextp);
    cvt_bf16_kernel<<<(N_NODES * 16 + 255) / 256, 256, 0, stream>>>(x, (unsigned*)xbf, N_NODES * 16);
    prep_w_kernel<<<(R_REL * 512 * 32 + 255) / 256, 256, 0, stream>>>(Wl1, Wr1, bl1, br1, Bt1, bc1, 32);
    prep_w_kernel<<<(R_REL * 512 * 128 + 255) / 256, 256, 0, stream>>>(Wl2, Wr2, bl2, br2, Bt2, bc2, 128);

    dim3 ggrid((N_NODES + 127) / 128, 4, R_REL);
    // ---- layer 1 ----
    gemm_mfma_kernel<32><<<ggrid, 256, 0, stream>>>(xbf, Bt1, bc1, xlr6);
    gat6_ln_kernel<<<N_NODES / 4, 256, 0, stream>>>(
        xlr6, headp, nextp, ei, att1, bias1, ln1g, ln1b, (unsigned*)h1bf);
    // ---- layer 2 ----
    gemm_mfma_kernel<128><<<ggrid, 256, 0, stream>>>(h1bf, Bt2, bc2, xlr6);
    gat6_ln_kernel<<<N_NODES / 4, 256, 0, stream>>>(
        xlr6, headp, nextp, ei, att2, bias2, ln2g, ln2b, (unsigned*)h1bf);
    // ---- pooling + projection ----
    pool_kernel<<<B_GRAPHS / 4, 256, 0, stream>>>((unsigned*)h1bf, query, gb);
    proj_kernel<<<B_GRAPHS, 128, 0, stream>>>(gb, projW, projb, out);
}

// Round 5
// 481.539 us; speedup vs baseline: 2.3847x; 1.0334x over previous
//
#include <hip/hip_runtime.h>
#include <math.h>

#define N_NODES 40000
#define E_EDGES 60000
#define R_REL 6
#define IN_F 32
#define HID_F 128
#define B_GRAPHS 2000
#define NODES_PER_G 20
#define NEG_SLOPE 0.2f
#define NB (R_REL * N_NODES)            // 240000 bins
#define NTOT (R_REL * (E_EDGES + N_NODES))  // 600000 entries incl. self-loops
#define NBLK ((NB + 255) / 256)         // 938 scan blocks

typedef __bf16 bf16x8 __attribute__((ext_vector_type(8)));
typedef float f32x4 __attribute__((ext_vector_type(4)));

__device__ __forceinline__ unsigned f2bfbits(float f) {
    unsigned u = __builtin_bit_cast(unsigned, f);
    return (u + 0x7FFFu + ((u >> 16) & 1u)) >> 16;   // RNE
}
__device__ __forceinline__ float bflo(unsigned u) { return __builtin_bit_cast(float, u << 16); }
__device__ __forceinline__ float bfhi(unsigned u) { return __builtin_bit_cast(float, u & 0xFFFF0000u); }

// ---------------- CSR build: count ----------------
__global__ __launch_bounds__(256) void count_kernel(
    const int* __restrict__ ei, int* __restrict__ cnt)
{
    int idx = blockIdx.x * 256 + threadIdx.x;
    if (idx >= NTOT) return;
    int bin;
    if (idx < R_REL * E_EDGES) {
        int r = idx / E_EDGES, e = idx - r * E_EDGES;
        bin = r * N_NODES + ei[(size_t)r * 2 * E_EDGES + E_EDGES + e];
    } else {
        bin = idx - R_REL * E_EDGES;   // self-loop: bin == r*N+d
    }
    atomicAdd(&cnt[bin], 1);
}

// ---------------- CSR build: scan level 1 (per-256 block) ----------------
__global__ __launch_bounds__(256) void scan1_kernel(
    const int* __restrict__ cnt, int* __restrict__ part, int* __restrict__ bsum)
{
    int i = blockIdx.x * 256 + threadIdx.x;
    int v = (i < NB) ? cnt[i] : 0;
    int lane = threadIdx.x & 63, w = threadIdx.x >> 6;
    int x = v;
#pragma unroll
    for (int off = 1; off < 64; off <<= 1) {
        int y = __shfl_up(x, off, 64);
        if (lane >= off) x += y;
    }
    __shared__ int ws[4];
    if (lane == 63) ws[w] = x;
    __syncthreads();
    int add = 0;
    for (int j = 0; j < w; j++) add += ws[j];
    int incl = x + add;
    if (i < NB) part[i] = incl - v;           // exclusive within block
    if (threadIdx.x == 255) bsum[blockIdx.x] = incl;
}

// ---------------- CSR build: scan level 2 (block sums, single block) ---------
__global__ __launch_bounds__(1024) void scan2_kernel(
    const int* __restrict__ bsum, int* __restrict__ boff)
{
    __shared__ int buf[1024];
    int t = threadIdx.x;
    int v0 = (t < NBLK) ? bsum[t] : 0;
    buf[t] = v0;
    __syncthreads();
    for (int off = 1; off < 1024; off <<= 1) {
        int v = (t >= off) ? buf[t - off] : 0;
        __syncthreads();
        buf[t] += v;
        __syncthreads();
    }
    if (t < NBLK) boff[t] = buf[t] - v0;      // exclusive
}

// ---------------- CSR build: finalize rowptr + cursor ----------------
__global__ __launch_bounds__(256) void scan3_kernel(
    const int* __restrict__ part, const int* __restrict__ boff,
    int* __restrict__ rowptr, int* __restrict__ cursor)
{
    int i = blockIdx.x * 256 + threadIdx.x;
    if (i < NB) {
        int v = part[i] + boff[i >> 8];
        rowptr[i] = v;
        cursor[i] = v;
    }
    if (i == 0) rowptr[NB] = NTOT;
}

// ---------------- CSR build: scatter (edges + self-loops) ----------------
__global__ __launch_bounds__(256) void scatter_kernel(
    const int* __restrict__ ei, int* __restrict__ cursor, int* __restrict__ csr)
{
    int idx = blockIdx.x * 256 + threadIdx.x;
    if (idx >= NTOT) return;
    int bin, src;
    if (idx < R_REL * E_EDGES) {
        int r = idx / E_EDGES, e = idx - r * E_EDGES;
        src = ei[(size_t)r * 2 * E_EDGES + e];
        bin = r * N_NODES + ei[(size_t)r * 2 * E_EDGES + E_EDGES + e];
    } else {
        bin = idx - R_REL * E_EDGES;
        src = bin % N_NODES;
    }
    int pos = atomicAdd(&cursor[bin], 1);
    csr[pos] = src;
}

// ---------------- prep: fp32 -> bf16 pairwise ----------------
__global__ __launch_bounds__(256) void cvt_bf16_kernel(
    const float* __restrict__ src, unsigned* __restrict__ dst, int npairs)
{
    int i = blockIdx.x * 256 + threadIdx.x;
    if (i >= npairs) return;
    float2 v = *(const float2*)(src + 2 * i);
    dst[i] = f2bfbits(v.x) | (f2bfbits(v.y) << 16);
}

// ---------------- prep: W[r][k][256] (l|r) -> Bt[r][512][K] bf16, bias cat ----
__global__ __launch_bounds__(256) void prep_w_kernel(
    const float* __restrict__ Wl, const float* __restrict__ Wr,
    const float* __restrict__ bl, const float* __restrict__ br,
    unsigned short* __restrict__ Bt, float* __restrict__ bcat, int K)
{
    int idx = blockIdx.x * 256 + threadIdx.x;
    if (idx >= R_REL * 512 * K) return;
    int k = idx % K;
    int rn = idx / K;
    int n = rn % 512;
    int r = rn / 512;
    int nn = n & 255;
    const float* W = (n < 256) ? Wl : Wr;
    float w = W[((size_t)r * K + k) * 256 + nn];
    Bt[idx] = (unsigned short)f2bfbits(w);
    if (k == 0)
        bcat[rn] = (n < 256) ? bl[r * 256 + nn] : br[r * 256 + nn];
}

// ---------------- MFMA GEMM over all 6 relations (blockIdx.z = relation) ------
template <int K>
__global__ __launch_bounds__(256) void gemm_mfma_kernel(
    const unsigned short* __restrict__ A,
    const unsigned short* __restrict__ BtAll,   // [R][512][K] bf16 (n-major)
    const float* __restrict__ biasAll,          // [R][512]
    unsigned short* __restrict__ CAll)          // [R][40000][512]
{
    __shared__ char lds[16384];
    char* ldsA = lds;
    char* ldsB = lds + 8192;
    const unsigned short* Bt = BtAll + (size_t)blockIdx.z * 512 * K;
    const float* bias = biasAll + blockIdx.z * 512;
    unsigned short* C = CAll + (size_t)blockIdx.z * N_NODES * 512;
    int tid = threadIdx.x;
    int lane = tid & 63, wave = tid >> 6;
    int l16 = lane & 15, quad = lane >> 4;
    int wm = (wave >> 1) * 64, wn = (wave & 1) * 64;
    int m0 = blockIdx.x * 128;
    int n0 = blockIdx.y * 128;

    f32x4 acc[4][4] = {};

    for (int k0 = 0; k0 < K; k0 += 32) {
#pragma unroll
        for (int j = 0; j < 2; j++) {
            int o = wave * 2048 + j * 1024;
            int boff = o + lane * 16;
            int row = boff >> 6, ko = boff & 63;
            int gr = m0 + row;
            gr = gr < N_NODES ? gr : (N_NODES - 1);
            const char* gpA = (const char*)A + (size_t)gr * (K * 2) + k0 * 2 + ko;
            __builtin_amdgcn_global_load_lds(
                (const __attribute__((address_space(1))) void*)gpA,
                (__attribute__((address_space(3))) void*)(ldsA + o), 16, 0, 0);
            const char* gpB = (const char*)Bt + (size_t)(n0 + row) * (K * 2) + k0 * 2 + ko;
            __builtin_amdgcn_global_load_lds(
                (const __attribute__((address_space(1))) void*)gpB,
                (__attribute__((address_space(3))) void*)(ldsB + o), 16, 0, 0);
        }
        __syncthreads();
        bf16x8 af[4], bfr[4];
#pragma unroll
        for (int i = 0; i < 4; i++)
            af[i] = *(const bf16x8*)(ldsA + (wm + i * 16 + l16) * 64 + quad * 16);
#pragma unroll
        for (int j = 0; j < 4; j++)
            bfr[j] = *(const bf16x8*)(ldsB + (wn + j * 16 + l16) * 64 + quad * 16);
#pragma unroll
        for (int i = 0; i < 4; i++)
#pragma unroll
            for (int j = 0; j < 4; j++)
                acc[i][j] = __builtin_amdgcn_mfma_f32_16x16x32_bf16(af[i], bfr[j], acc[i][j], 0, 0, 0);
        __syncthreads();
    }

    float biasj[4];
#pragma unroll
    for (int j = 0; j < 4; j++) biasj[j] = bias[n0 + wn + j * 16 + l16];
#pragma unroll
    for (int i = 0; i < 4; i++) {
        int gr0 = m0 + wm + i * 16 + quad * 4;
#pragma unroll
        for (int j = 0; j < 4; j++) {
            int col = n0 + wn + j * 16 + l16;
#pragma unroll
            for (int rg = 0; rg < 4; rg++) {
                float a = acc[i][j][rg] + biasj[j];
                float b = __shfl_xor(a, 1);
                int grow = gr0 + rg;
                if (!(lane & 1) && grow < N_NODES) {
                    unsigned u = f2bfbits(a) | (f2bfbits(b) << 16);
                    *(unsigned*)((char*)C + ((size_t)grow * 512 + col) * 2) = u;
                }
            }
        }
    }
}

// ------- fused 6-relation GATv2 + relation-sum + tanh + LayerNorm, CSR --------
// XLR row (512 bf16 = 1024 B): [0:512)B = xl (head0|head1), [512:1024)B = xr
// lanes 0-31 own head0 (4 ch each), lanes 32-63 own head1.
// CSR includes self-loops; edges processed pairwise with independent accumulators.
__global__ __launch_bounds__(256) void gat6_ln_kernel(
    const unsigned short* __restrict__ XLR,
    const int* __restrict__ rowptr,   // [R*N+1]
    const int* __restrict__ csr,      // [NTOT] src indices
    const float* __restrict__ att,    // [R][2][128]
    const float* __restrict__ bias,   // [R][128]
    const float* __restrict__ lng, const float* __restrict__ lnb,
    unsigned* __restrict__ hout)      // [N][64] packed bf16 pairs
{
    int gtid = blockIdx.x * 256 + threadIdx.x;
    int d = gtid >> 6;
    int lane = threadIdx.x & 63;
    if (d >= N_NODES) return;
    int hl = lane & 31;

    float tot0 = 0.f, tot1 = 0.f, tot2 = 0.f, tot3 = 0.f;
#pragma unroll 1
    for (int r = 0; r < R_REL; r++) {
        const char* base = (const char*)XLR + (size_t)r * N_NODES * 1024;
        const unsigned* xrp = (const unsigned*)(base + (size_t)d * 1024 + 512 + lane * 8);
        unsigned xu0 = xrp[0], xu1 = xrp[1];
        float xr0 = bflo(xu0), xr1 = bfhi(xu0), xr2 = bflo(xu1), xr3 = bfhi(xu1);
        float4 av = *(const float4*)(att + r * 256 + lane * 4);

        int bin = r * N_NODES + d;
        int beg = __builtin_amdgcn_readfirstlane(rowptr[bin]);
        int end = __builtin_amdgcn_readfirstlane(rowptr[bin + 1]);

        float sA = 0.f, a0 = 0.f, a1 = 0.f, a2 = 0.f, a3 = 0.f;
        float sB = 0.f, b0 = 0.f, b1 = 0.f, b2 = 0.f, b3 = 0.f;
        int i = beg;
        for (; i + 2 <= end; i += 2) {
            int s0 = csr[i], s1 = csr[i + 1];
            const unsigned* pA = (const unsigned*)(base + (size_t)s0 * 1024 + lane * 8);
            const unsigned* pB = (const unsigned*)(base + (size_t)s1 * 1024 + lane * 8);
            unsigned uA0 = pA[0], uA1 = pA[1];
            unsigned uB0 = pB[0], uB1 = pB[1];
            float xA0 = bflo(uA0), xA1 = bfhi(uA0), xA2 = bflo(uA1), xA3 = bfhi(uA1);
            float xB0 = bflo(uB0), xB1 = bfhi(uB0), xB2 = bflo(uB1), xB3 = bfhi(uB1);
            float tA0 = xA0 + xr0, tA1 = xA1 + xr1, tA2 = xA2 + xr2, tA3 = xA3 + xr3;
            float tB0 = xB0 + xr0, tB1 = xB1 + xr1, tB2 = xB2 + xr2, tB3 = xB3 + xr3;
            tA0 = fmaxf(tA0, NEG_SLOPE * tA0); tB0 = fmaxf(tB0, NEG_SLOPE * tB0);
            tA1 = fmaxf(tA1, NEG_SLOPE * tA1); tB1 = fmaxf(tB1, NEG_SLOPE * tB1);
            tA2 = fmaxf(tA2, NEG_SLOPE * tA2); tB2 = fmaxf(tB2, NEG_SLOPE * tB2);
            tA3 = fmaxf(tA3, NEG_SLOPE * tA3); tB3 = fmaxf(tB3, NEG_SLOPE * tB3);
            float pa = tA0 * av.x + tA1 * av.y + tA2 * av.z + tA3 * av.w;
            float pb = tB0 * av.x + tB1 * av.y + tB2 * av.z + tB3 * av.w;
            pa += __shfl_xor(pa, 16); pb += __shfl_xor(pb, 16);
            pa += __shfl_xor(pa, 8);  pb += __shfl_xor(pb, 8);
            pa += __shfl_xor(pa, 4);  pb += __shfl_xor(pb, 4);
            pa += __shfl_xor(pa, 2);  pb += __shfl_xor(pb, 2);
            pa += __shfl_xor(pa, 1);  pb += __shfl_xor(pb, 1);
            float wa = __expf(fminf(pa, 60.f));
            float wb = __expf(fminf(pb, 60.f));
            sA += wa; sB += wb;
            a0 = fmaf(wa, xA0, a0); b0 = fmaf(wb, xB0, b0);
            a1 = fmaf(wa, xA1, a1); b1 = fmaf(wb, xB1, b1);
            a2 = fmaf(wa, xA2, a2); b2 = fmaf(wb, xB2, b2);
            a3 = fmaf(wa, xA3, a3); b3 = fmaf(wb, xB3, b3);
        }
        if (i < end) {
            int s0 = csr[i];
            const unsigned* pA = (const unsigned*)(base + (size_t)s0 * 1024 + lane * 8);
            unsigned uA0 = pA[0], uA1 = pA[1];
            float xA0 = bflo(uA0), xA1 = bfhi(uA0), xA2 = bflo(uA1), xA3 = bfhi(uA1);
            float tA0 = xA0 + xr0, tA1 = xA1 + xr1, tA2 = xA2 + xr2, tA3 = xA3 + xr3;
            tA0 = fmaxf(tA0, NEG_SLOPE * tA0);
            tA1 = fmaxf(tA1, NEG_SLOPE * tA1);
            tA2 = fmaxf(tA2, NEG_SLOPE * tA2);
            tA3 = fmaxf(tA3, NEG_SLOPE * tA3);
            float pa = tA0 * av.x + tA1 * av.y + tA2 * av.z + tA3 * av.w;
            pa += __shfl_xor(pa, 16);
            pa += __shfl_xor(pa, 8);
            pa += __shfl_xor(pa, 4);
            pa += __shfl_xor(pa, 2);
            pa += __shfl_xor(pa, 1);
            float wa = __expf(fminf(pa, 60.f));
            sA += wa;
            a0 = fmaf(wa, xA0, a0);
            a1 = fmaf(wa, xA1, a1);
            a2 = fmaf(wa, xA2, a2);
            a3 = fmaf(wa, xA3, a3);
        }
        sA += sB; a0 += b0; a1 += b1; a2 += b2; a3 += b3;
        float rs = 0.5f * __builtin_amdgcn_rcpf(sA);   // fold head-mean 0.5
        float o0 = a0 * rs, o1 = a1 * rs, o2 = a2 * rs, o3 = a3 * rs;
        o0 += __shfl_xor(o0, 32);
        o1 += __shfl_xor(o1, 32);
        o2 += __shfl_xor(o2, 32);
        o3 += __shfl_xor(o3, 32);
        float4 bv = *(const float4*)(bias + r * 128 + hl * 4);
        tot0 += o0 + bv.x;
        tot1 += o1 + bv.y;
        tot2 += o2 + bv.z;
        tot3 += o3 + bv.w;
    }
    // tanh + layernorm (128 ch replicated in each 32-lane half)
    float v0 = tanhf(tot0), v1 = tanhf(tot1), v2 = tanhf(tot2), v3 = tanhf(tot3);
    float sum = v0 + v1 + v2 + v3;
    float sq = v0 * v0 + v1 * v1 + v2 * v2 + v3 * v3;
#pragma unroll
    for (int off = 16; off >= 1; off >>= 1) {
        sum += __shfl_xor(sum, off);
        sq  += __shfl_xor(sq, off);
    }
    float mean = sum * (1.f / 128.f);
    float var = sq * (1.f / 128.f) - mean * mean;
    float rstd = rsqrtf(var + 1e-5f);
    float4 gg = *(const float4*)(lng + hl * 4);
    float4 bb = *(const float4*)(lnb + hl * 4);
    float o0 = (v0 - mean) * rstd * gg.x + bb.x;
    float o1 = (v1 - mean) * rstd * gg.y + bb.y;
    float o2 = (v2 - mean) * rstd * gg.z + bb.z;
    float o3 = (v3 - mean) * rstd * gg.w + bb.w;
    if (lane < 32) {
        uint2 q;
        q.x = f2bfbits(o0) | (f2bfbits(o1) << 16);
        q.y = f2bfbits(o2) | (f2bfbits(o3) << 16);
        *((uint2*)(hout + (size_t)d * 64) + hl) = q;
    }
}

// ---------------- attention pooling over bf16 h: one wave per graph -----------
__global__ __launch_bounds__(256) void pool_kernel(
    const unsigned* __restrict__ hb, const float* __restrict__ query,
    float* __restrict__ gout)
{
    int gtid = blockIdx.x * 256 + threadIdx.x;
    int bg = gtid >> 6;
    int lane = threadIdx.x & 63;
    if (bg >= B_GRAPHS) return;
    float2 q = *(const float2*)(query + 2 * lane);
    float mx = -1e30f, ssum = 0.f, g0 = 0.f, g1 = 0.f;
    for (int i = 0; i < NODES_PER_G; i++) {
        unsigned u = hb[(size_t)(bg * NODES_PER_G + i) * 64 + lane];
        float h0 = bflo(u), h1 = bfhi(u);
        float p = h0 * q.x + h1 * q.y;
#pragma unroll
        for (int off = 32; off >= 1; off >>= 1) p += __shfl_xor(p, off, 64);
        float mn = fmaxf(mx, p);
        float sc = __expf(mx - mn), w = __expf(p - mn);
        ssum = ssum * sc + w;
        g0 = g0 * sc + w * h0;
        g1 = g1 * sc + w * h1;
        mx = mn;
    }
    float2 o; o.x = g0 / ssum; o.y = g1 / ssum;
    *(float2*)(gout + (size_t)bg * 128 + 2 * lane) = o;
}

// ---------------- final projection ----------------
__global__ __launch_bounds__(128) void proj_kernel(
    const float* __restrict__ g, const float* __restrict__ W,
    const float* __restrict__ bias, float* __restrict__ out)
{
    int bg = blockIdx.x;
    int o = threadIdx.x;
    const float* gp = g + (size_t)bg * 128;
    float acc = bias[o];
    for (int k = 0; k < 128; k++) acc = fmaf(gp[k], W[k * 128 + o], acc);
    out[(size_t)bg * 128 + o] = acc;
}

extern "C" void kernel_launch(void* const* d_in, const int* in_sizes, int n_in,
                              void* d_out, int out_size, void* d_ws, size_t ws_size,
                              hipStream_t stream)
{
    const float* x     = (const float*)d_in[0];
    const int*   ei    = (const int*)d_in[1];
    const float* Wl1   = (const float*)d_in[3];
    const float* bl1   = (const float*)d_in[4];
    const float* Wr1   = (const float*)d_in[5];
    const float* br1   = (const float*)d_in[6];
    const float* att1  = (const float*)d_in[7];
    const float* bias1 = (const float*)d_in[8];
    const float* Wl2   = (const float*)d_in[9];
    const float* bl2   = (const float*)d_in[10];
    const float* Wr2   = (const float*)d_in[11];
    const float* br2   = (const float*)d_in[12];
    const float* att2  = (const float*)d_in[13];
    const float* bias2 = (const float*)d_in[14];
    const float* ln1g  = (const float*)d_in[15];
    const float* ln1b  = (const float*)d_in[16];
    const float* ln2g  = (const float*)d_in[17];
    const float* ln2b  = (const float*)d_in[18];
    const float* query = (const float*)d_in[19];
    const float* projW = (const float*)d_in[20];
    const float* projb = (const float*)d_in[21];
    float* out = (float*)d_out;

    // workspace layout — 266.8 MB of the 268.4 MB budget, all rewritten per call
    unsigned short* xlr6 = (unsigned short*)d_ws;                 // 245.76 MB
    unsigned short* h1bf = xlr6 + (size_t)R_REL * N_NODES * 512;  // 10.24 MB
    unsigned short* xbf  = h1bf + (size_t)N_NODES * 128;          // 2.56 MB
    unsigned short* Bt1  = xbf + (size_t)N_NODES * 32;
    unsigned short* Bt2  = Bt1 + R_REL * 512 * 32;
    float* bc1  = (float*)(Bt2 + R_REL * 512 * 128);
    float* bc2  = bc1 + R_REL * 512;
    float* gb   = bc2 + R_REL * 512;                              // 2000*128 f32
    int* cnt    = (int*)(gb + (size_t)B_GRAPHS * 128);            // NB
    int* part   = cnt + NB;                                       // NB
    int* rowptr = part + NB;                                      // NB+1
    int* cursor = rowptr + NB + 1;                                // NB
    int* bsum   = cursor + NB;                                    // NBLK
    int* boff   = bsum + NBLK;                                    // NBLK
    int* csr    = boff + NBLK;                                    // NTOT

    // ---- CSR build ----
    hipMemsetAsync(cnt, 0, sizeof(int) * NB, stream);
    count_kernel<<<(NTOT + 255) / 256, 256, 0, stream>>>(ei, cnt);
    scan1_kernel<<<NBLK, 256, 0, stream>>>(cnt, part, bsum);
    scan2_kernel<<<1, 1024, 0, stream>>>(bsum, boff);
    scan3_kernel<<<NBLK, 256, 0, stream>>>(part, boff, rowptr, cursor);
    scatter_kernel<<<(NTOT + 255) / 256, 256, 0, stream>>>(ei, cursor, csr);

    // ---- prep ----
    cvt_bf16_kernel<<<(N_NODES * 16 + 255) / 256, 256, 0, stream>>>(x, (unsigned*)xbf, N_NODES * 16);
    prep_w_kernel<<<(R_REL * 512 * 32 + 255) / 256, 256, 0, stream>>>(Wl1, Wr1, bl1, br1, Bt1, bc1, 32);
    prep_w_kernel<<<(R_REL * 512 * 128 + 255) / 256, 256, 0, stream>>>(Wl2, Wr2, bl2, br2, Bt2, bc2, 128);

    dim3 ggrid((N_NODES + 127) / 128, 4, R_REL);
    // ---- layer 1 ----
    gemm_mfma_kernel<32><<<ggrid, 256, 0, stream>>>(xbf, Bt1, bc1, xlr6);
    gat6_ln_kernel<<<N_NODES / 4, 256, 0, stream>>>(
        xlr6, rowptr, csr, att1, bias1, ln1g, ln1b, (unsigned*)h1bf);
    // ---- layer 2 ----
    gemm_mfma_kernel<128><<<ggrid, 256, 0, stream>>>(h1bf, Bt2, bc2, xlr6);
    gat6_ln_kernel<<<N_NODES / 4, 256, 0, stream>>>(
        xlr6, rowptr, csr, att2, bias2, ln2g, ln2b, (unsigned*)h1bf);
    // ---- pooling + projection ----
    pool_kernel<<<B_GRAPHS / 4, 256, 0, stream>>>((unsigned*)h1bf, query, gb);
    proj_kernel<<<B_GRAPHS, 128, 0, stream>>>(gb, projW, projb, out);
}

// Round 6
// 479.893 us; speedup vs baseline: 2.3929x; 1.0034x over previous
//
#include <hip/hip_runtime.h>
#include <hip/hip_bf16.h>
#include <math.h>

#define N_NODES 40000
#define E_EDGES 60000
#define R_REL 6
#define IN_F 32
#define HID_F 128
#define B_GRAPHS 2000
#define NODES_PER_G 20
#define NEG_SLOPE 0.2f
#define NB (R_REL * N_NODES)            // 240000 bins
#define NTOT (R_REL * (E_EDGES + N_NODES))  // 600000 entries incl. self-loops
#define NBLK ((NB + 255) / 256)         // 938 scan blocks

typedef __bf16 bf16x8 __attribute__((ext_vector_type(8)));
typedef float f32x4 __attribute__((ext_vector_type(4)));

__device__ __forceinline__ unsigned f2bfbits(float f) {
    unsigned u = __builtin_bit_cast(unsigned, f);
    return (u + 0x7FFFu + ((u >> 16) & 1u)) >> 16;   // RNE
}
__device__ __forceinline__ float bflo(unsigned u) { return __builtin_bit_cast(float, u << 16); }
__device__ __forceinline__ float bfhi(unsigned u) { return __builtin_bit_cast(float, u & 0xFFFF0000u); }

// ---------------- CSR build: count ----------------
__global__ __launch_bounds__(256) void count_kernel(
    const int* __restrict__ ei, int* __restrict__ cnt)
{
    int idx = blockIdx.x * 256 + threadIdx.x;
    if (idx >= NTOT) return;
    int bin;
    if (idx < R_REL * E_EDGES) {
        int r = idx / E_EDGES, e = idx - r * E_EDGES;
        bin = r * N_NODES + ei[(size_t)r * 2 * E_EDGES + E_EDGES + e];
    } else {
        bin = idx - R_REL * E_EDGES;   // self-loop: bin == r*N+d
    }
    atomicAdd(&cnt[bin], 1);
}

// ---------------- CSR build: scan level 1 (per-256 block) ----------------
__global__ __launch_bounds__(256) void scan1_kernel(
    const int* __restrict__ cnt, int* __restrict__ part, int* __restrict__ bsum)
{
    int i = blockIdx.x * 256 + threadIdx.x;
    int v = (i < NB) ? cnt[i] : 0;
    int lane = threadIdx.x & 63, w = threadIdx.x >> 6;
    int x = v;
#pragma unroll
    for (int off = 1; off < 64; off <<= 1) {
        int y = __shfl_up(x, off, 64);
        if (lane >= off) x += y;
    }
    __shared__ int ws[4];
    if (lane == 63) ws[w] = x;
    __syncthreads();
    int add = 0;
    for (int j = 0; j < w; j++) add += ws[j];
    int incl = x + add;
    if (i < NB) part[i] = incl - v;           // exclusive within block
    if (threadIdx.x == 255) bsum[blockIdx.x] = incl;
}

// ---------------- CSR build: scan level 2 (block sums, single block) ---------
__global__ __launch_bounds__(1024) void scan2_kernel(
    const int* __restrict__ bsum, int* __restrict__ boff)
{
    __shared__ int buf[1024];
    int t = threadIdx.x;
    int v0 = (t < NBLK) ? bsum[t] : 0;
    buf[t] = v0;
    __syncthreads();
    for (int off = 1; off < 1024; off <<= 1) {
        int v = (t >= off) ? buf[t - off] : 0;
        __syncthreads();
        buf[t] += v;
        __syncthreads();
    }
    if (t < NBLK) boff[t] = buf[t] - v0;      // exclusive
}

// ---------------- CSR build: finalize rowptr + cursor ----------------
__global__ __launch_bounds__(256) void scan3_kernel(
    const int* __restrict__ part, const int* __restrict__ boff,
    int* __restrict__ rowptr, int* __restrict__ cursor)
{
    int i = blockIdx.x * 256 + threadIdx.x;
    if (i < NB) {
        int v = part[i] + boff[i >> 8];
        rowptr[i] = v;
        cursor[i] = v;
    }
    if (i == 0) rowptr[NB] = NTOT;
}

// ---------------- CSR build: scatter (edges + self-loops) ----------------
__global__ __launch_bounds__(256) void scatter_kernel(
    const int* __restrict__ ei, int* __restrict__ cursor, int* __restrict__ csr)
{
    int idx = blockIdx.x * 256 + threadIdx.x;
    if (idx >= NTOT) return;
    int bin, src;
    if (idx < R_REL * E_EDGES) {
        int r = idx / E_EDGES, e = idx - r * E_EDGES;
        src = ei[(size_t)r * 2 * E_EDGES + e];
        bin = r * N_NODES + ei[(size_t)r * 2 * E_EDGES + E_EDGES + e];
    } else {
        bin = idx - R_REL * E_EDGES;
        src = bin % N_NODES;
    }
    int pos = atomicAdd(&cursor[bin], 1);
    csr[pos] = src;
}

// ---------------- prep: fp32 -> bf16 pairwise ----------------
__global__ __launch_bounds__(256) void cvt_bf16_kernel(
    const float* __restrict__ src, unsigned* __restrict__ dst, int npairs)
{
    int i = blockIdx.x * 256 + threadIdx.x;
    if (i >= npairs) return;
    float2 v = *(const float2*)(src + 2 * i);
    dst[i] = f2bfbits(v.x) | (f2bfbits(v.y) << 16);
}

// ---------------- prep: W[r][k][256] (l|r) -> Bt[r][512][K] bf16, bias cat ----
__global__ __launch_bounds__(256) void prep_w_kernel(
    const float* __restrict__ Wl, const float* __restrict__ Wr,
    const float* __restrict__ bl, const float* __restrict__ br,
    unsigned short* __restrict__ Bt, float* __restrict__ bcat, int K)
{
    int idx = blockIdx.x * 256 + threadIdx.x;
    if (idx >= R_REL * 512 * K) return;
    int k = idx % K;
    int rn = idx / K;
    int n = rn % 512;
    int r = rn / 512;
    int nn = n & 255;
    const float* W = (n < 256) ? Wl : Wr;
    float w = W[((size_t)r * K + k) * 256 + nn];
    Bt[idx] = (unsigned short)f2bfbits(w);
    if (k == 0)
        bcat[rn] = (n < 256) ? bl[r * 256 + nn] : br[r * 256 + nn];
}

// ---------------- MFMA GEMM: A staged once, z-loop over relations -------------
// A LDS layout: row-major, 16-B chunks XOR-swizzled by row (bank spread).
// B double-buffered 2x8KB, prefetched one k-iter ahead.
template <int K, int ZPB>
__global__ __launch_bounds__(256) void gemm_mfma_kernel(
    const unsigned short* __restrict__ A,
    const unsigned short* __restrict__ BtAll,   // [R][512][K] bf16 (n-major)
    const float* __restrict__ biasAll,          // [R][512]
    unsigned short* __restrict__ CAll)          // [R][40000][512]
{
    constexpr int CHUNKS = K / 8;               // 16-B chunks per A row
    constexpr int ABYTES = 128 * K * 2;
    __shared__ char lds[ABYTES + 16384];
    char* ldsA = lds;
    char* ldsB = lds + ABYTES;

    int tid = threadIdx.x;
    int lane = tid & 63, wave = tid >> 6;
    int l16 = lane & 15, quad = lane >> 4;
    int wm = (wave >> 1) * 64, wn = (wave & 1) * 64;
    int m0 = blockIdx.x * 128, n0 = blockIdx.y * 128;
    int zbase = blockIdx.z * ZPB;

    // ---- stage A: full K, chunk-swizzled ----
#pragma unroll
    for (int it = 0; it < (128 * CHUNKS) / 256; ++it) {
        int s = it * 256 + tid;
        int row = s / CHUNKS, sc = s % CHUNKS;
        int sw = (K == 128) ? (row & 7) : ((row >> 1) & 3);
        int c = sc ^ sw;
        int gr = m0 + row; gr = gr < N_NODES ? gr : N_NODES - 1;
        const char* gp = (const char*)A + (size_t)gr * (K * 2) + c * 16;
        __builtin_amdgcn_global_load_lds(
            (const __attribute__((address_space(1))) void*)gp,
            (__attribute__((address_space(3))) void*)(ldsA + it * 4096 + wave * 1024), 16, 0, 0);
    }

    auto stageB = [&](int z, int k0, int pb) {
        const char* Bt = (const char*)(BtAll + (size_t)(zbase + z) * 512 * K);
#pragma unroll
        for (int it = 0; it < 2; ++it) {
            int s = it * 256 + tid;
            int row = s >> 2, sc = s & 3;
            int c = sc ^ ((row >> 1) & 3);
            const char* gp = Bt + (size_t)(n0 + row) * (K * 2) + k0 * 2 + c * 16;
            __builtin_amdgcn_global_load_lds(
                (const __attribute__((address_space(1))) void*)gp,
                (__attribute__((address_space(3))) void*)(ldsB + pb * 8192 + it * 4096 + wave * 1024), 16, 0, 0);
        }
    };

    stageB(0, 0, 0);
    __syncthreads();

    int p = 0;
    for (int z = 0; z < ZPB; ++z) {
        f32x4 acc[4][4];
#pragma unroll
        for (int i = 0; i < 4; i++)
#pragma unroll
            for (int j = 0; j < 4; j++) {
                acc[i][j][0] = 0.f; acc[i][j][1] = 0.f;
                acc[i][j][2] = 0.f; acc[i][j][3] = 0.f;
            }

        for (int k0 = 0; k0 < K; k0 += 32) {
            int nz = (k0 + 32 < K) ? z : z + 1;
            int nk = (k0 + 32 < K) ? k0 + 32 : 0;
            if (nz < ZPB) stageB(nz, nk, p ^ 1);   // prefetch overlaps compute

            bf16x8 af[4], bfr[4];
#pragma unroll
            for (int i = 0; i < 4; i++) {
                int row = wm + i * 16 + l16;
                int sw = (K == 128) ? (row & 7) : ((row >> 1) & 3);
                int c = (k0 / 8 + quad) ^ sw;
                af[i] = *(const bf16x8*)(ldsA + row * (K * 2) + c * 16);
            }
#pragma unroll
            for (int j = 0; j < 4; j++) {
                int row = wn + j * 16 + l16;
                int c = quad ^ ((row >> 1) & 3);
                bfr[j] = *(const bf16x8*)(ldsB + p * 8192 + row * 64 + c * 16);
            }
#pragma unroll
            for (int i = 0; i < 4; i++)
#pragma unroll
                for (int j = 0; j < 4; j++)
                    acc[i][j] = __builtin_amdgcn_mfma_f32_16x16x32_bf16(af[i], bfr[j], acc[i][j], 0, 0, 0);
            __syncthreads();
            p ^= 1;
        }

        // ---- epilogue for relation z: packed bf16 cvt + 4-B stores ----
        const float* bias = biasAll + (zbase + z) * 512;
        unsigned short* C = CAll + (size_t)(zbase + z) * N_NODES * 512;
        float biasj[4];
#pragma unroll
        for (int j = 0; j < 4; j++) biasj[j] = bias[n0 + wn + j * 16 + l16];
#pragma unroll
        for (int i = 0; i < 4; i++) {
            int gr0 = m0 + wm + i * 16 + quad * 4;
#pragma unroll
            for (int j = 0; j < 4; j++) {
                int col = n0 + wn + j * 16 + l16;
#pragma unroll
                for (int rg = 0; rg < 4; rg++) {
                    float a = acc[i][j][rg] + biasj[j];
                    float b = __shfl_xor(a, 1);
                    int grow = gr0 + rg;
                    if (!(lane & 1) && grow < N_NODES) {
                        __hip_bfloat162 h2 = __float22bfloat162_rn(make_float2(a, b));
                        unsigned u;
                        __builtin_memcpy(&u, &h2, 4);
                        *(unsigned*)((char*)C + ((size_t)grow * 512 + col) * 2) = u;
                    }
                }
            }
        }
    }
}

// ------- fused 6-relation GATv2 + relation-sum + tanh + LayerNorm, CSR --------
// XLR row (512 bf16 = 1024 B): [0:512)B = xl (head0|head1), [512:1024)B = xr
// lanes 0-31 own head0 (4 ch each), lanes 32-63 own head1.
// CSR includes self-loops; edges processed pairwise with independent accumulators.
__global__ __launch_bounds__(256) void gat6_ln_kernel(
    const unsigned short* __restrict__ XLR,
    const int* __restrict__ rowptr,   // [R*N+1]
    const int* __restrict__ csr,      // [NTOT] src indices
    const float* __restrict__ att,    // [R][2][128]
    const float* __restrict__ bias,   // [R][128]
    const float* __restrict__ lng, const float* __restrict__ lnb,
    unsigned* __restrict__ hout)      // [N][64] packed bf16 pairs
{
    int gtid = blockIdx.x * 256 + threadIdx.x;
    int d = gtid >> 6;
    int lane = threadIdx.x & 63;
    if (d >= N_NODES) return;
    int hl = lane & 31;

    float tot0 = 0.f, tot1 = 0.f, tot2 = 0.f, tot3 = 0.f;
#pragma unroll 1
    for (int r = 0; r < R_REL; r++) {
        const char* base = (const char*)XLR + (size_t)r * N_NODES * 1024;
        const unsigned* xrp = (const unsigned*)(base + (size_t)d * 1024 + 512 + lane * 8);
        unsigned xu0 = xrp[0], xu1 = xrp[1];
        float xr0 = bflo(xu0), xr1 = bfhi(xu0), xr2 = bflo(xu1), xr3 = bfhi(xu1);
        float4 av = *(const float4*)(att + r * 256 + lane * 4);

        int bin = r * N_NODES + d;
        int beg = __builtin_amdgcn_readfirstlane(rowptr[bin]);
        int end = __builtin_amdgcn_readfirstlane(rowptr[bin + 1]);

        float sA = 0.f, a0 = 0.f, a1 = 0.f, a2 = 0.f, a3 = 0.f;
        float sB = 0.f, b0 = 0.f, b1 = 0.f, b2 = 0.f, b3 = 0.f;
        int i = beg;
        for (; i + 2 <= end; i += 2) {
            int s0 = csr[i], s1 = csr[i + 1];
            const unsigned* pA = (const unsigned*)(base + (size_t)s0 * 1024 + lane * 8);
            const unsigned* pB = (const unsigned*)(base + (size_t)s1 * 1024 + lane * 8);
            unsigned uA0 = pA[0], uA1 = pA[1];
            unsigned uB0 = pB[0], uB1 = pB[1];
            float xA0 = bflo(uA0), xA1 = bfhi(uA0), xA2 = bflo(uA1), xA3 = bfhi(uA1);
            float xB0 = bflo(uB0), xB1 = bfhi(uB0), xB2 = bflo(uB1), xB3 = bfhi(uB1);
            float tA0 = xA0 + xr0, tA1 = xA1 + xr1, tA2 = xA2 + xr2, tA3 = xA3 + xr3;
            float tB0 = xB0 + xr0, tB1 = xB1 + xr1, tB2 = xB2 + xr2, tB3 = xB3 + xr3;
            tA0 = fmaxf(tA0, NEG_SLOPE * tA0); tB0 = fmaxf(tB0, NEG_SLOPE * tB0);
            tA1 = fmaxf(tA1, NEG_SLOPE * tA1); tB1 = fmaxf(tB1, NEG_SLOPE * tB1);
            tA2 = fmaxf(tA2, NEG_SLOPE * tA2); tB2 = fmaxf(tB2, NEG_SLOPE * tB2);
            tA3 = fmaxf(tA3, NEG_SLOPE * tA3); tB3 = fmaxf(tB3, NEG_SLOPE * tB3);
            float pa = tA0 * av.x + tA1 * av.y + tA2 * av.z + tA3 * av.w;
            float pb = tB0 * av.x + tB1 * av.y + tB2 * av.z + tB3 * av.w;
            pa += __shfl_xor(pa, 16); pb += __shfl_xor(pb, 16);
            pa += __shfl_xor(pa, 8);  pb += __shfl_xor(pb, 8);
            pa += __shfl_xor(pa, 4);  pb += __shfl_xor(pb, 4);
            pa += __shfl_xor(pa, 2);  pb += __shfl_xor(pb, 2);
            pa += __shfl_xor(pa, 1);  pb += __shfl_xor(pb, 1);
            float wa = __expf(fminf(pa, 60.f));
            float wb = __expf(fminf(pb, 60.f));
            sA += wa; sB += wb;
            a0 = fmaf(wa, xA0, a0); b0 = fmaf(wb, xB0, b0);
            a1 = fmaf(wa, xA1, a1); b1 = fmaf(wb, xB1, b1);
            a2 = fmaf(wa, xA2, a2); b2 = fmaf(wb, xB2, b2);
            a3 = fmaf(wa, xA3, a3); b3 = fmaf(wb, xB3, b3);
        }
        if (i < end) {
            int s0 = csr[i];
            const unsigned* pA = (const unsigned*)(base + (size_t)s0 * 1024 + lane * 8);
            unsigned uA0 = pA[0], uA1 = pA[1];
            float xA0 = bflo(uA0), xA1 = bfhi(uA0), xA2 = bflo(uA1), xA3 = bfhi(uA1);
            float tA0 = xA0 + xr0, tA1 = xA1 + xr1, tA2 = xA2 + xr2, tA3 = xA3 + xr3;
            tA0 = fmaxf(tA0, NEG_SLOPE * tA0);
            tA1 = fmaxf(tA1, NEG_SLOPE * tA1);
            tA2 = fmaxf(tA2, NEG_SLOPE * tA2);
            tA3 = fmaxf(tA3, NEG_SLOPE * tA3);
            float pa = tA0 * av.x + tA1 * av.y + tA2 * av.z + tA3 * av.w;
            pa += __shfl_xor(pa, 16);
            pa += __shfl_xor(pa, 8);
            pa += __shfl_xor(pa, 4);
            pa += __shfl_xor(pa, 2);
            pa += __shfl_xor(pa, 1);
            float wa = __expf(fminf(pa, 60.f));
            sA += wa;
            a0 = fmaf(wa, xA0, a0);
            a1 = fmaf(wa, xA1, a1);
            a2 = fmaf(wa, xA2, a2);
            a3 = fmaf(wa, xA3, a3);
        }
        sA += sB; a0 += b0; a1 += b1; a2 += b2; a3 += b3;
        float rs = 0.5f * __builtin_amdgcn_rcpf(sA);   // fold head-mean 0.5
        float o0 = a0 * rs, o1 = a1 * rs, o2 = a2 * rs, o3 = a3 * rs;
        o0 += __shfl_xor(o0, 32);
        o1 += __shfl_xor(o1, 32);
        o2 += __shfl_xor(o2, 32);
        o3 += __shfl_xor(o3, 32);
        float4 bv = *(const float4*)(bias + r * 128 + hl * 4);
        tot0 += o0 + bv.x;
        tot1 += o1 + bv.y;
        tot2 += o2 + bv.z;
        tot3 += o3 + bv.w;
    }
    // tanh + layernorm (128 ch replicated in each 32-lane half)
    float v0 = tanhf(tot0), v1 = tanhf(tot1), v2 = tanhf(tot2), v3 = tanhf(tot3);
    float sum = v0 + v1 + v2 + v3;
    float sq = v0 * v0 + v1 * v1 + v2 * v2 + v3 * v3;
#pragma unroll
    for (int off = 16; off >= 1; off >>= 1) {
        sum += __shfl_xor(sum, off);
        sq  += __shfl_xor(sq, off);
    }
    float mean = sum * (1.f / 128.f);
    float var = sq * (1.f / 128.f) - mean * mean;
    float rstd = rsqrtf(var + 1e-5f);
    float4 gg = *(const float4*)(lng + hl * 4);
    float4 bb = *(const float4*)(lnb + hl * 4);
    float o0 = (v0 - mean) * rstd * gg.x + bb.x;
    float o1 = (v1 - mean) * rstd * gg.y + bb.y;
    float o2 = (v2 - mean) * rstd * gg.z + bb.z;
    float o3 = (v3 - mean) * rstd * gg.w + bb.w;
    if (lane < 32) {
        uint2 q;
        q.x = f2bfbits(o0) | (f2bfbits(o1) << 16);
        q.y = f2bfbits(o2) | (f2bfbits(o3) << 16);
        *((uint2*)(hout + (size_t)d * 64) + hl) = q;
    }
}

// ---------------- attention pooling over bf16 h: one wave per graph -----------
__global__ __launch_bounds__(256) void pool_kernel(
    const unsigned* __restrict__ hb, const float* __restrict__ query,
    float* __restrict__ gout)
{
    int gtid = blockIdx.x * 256 + threadIdx.x;
    int bg = gtid >> 6;
    int lane = threadIdx.x & 63;
    if (bg >= B_GRAPHS) return;
    float2 q = *(const float2*)(query + 2 * lane);
    float mx = -1e30f, ssum = 0.f, g0 = 0.f, g1 = 0.f;
    for (int i = 0; i < NODES_PER_G; i++) {
        unsigned u = hb[(size_t)(bg * NODES_PER_G + i) * 64 + lane];
        float h0 = bflo(u), h1 = bfhi(u);
        float p = h0 * q.x + h1 * q.y;
#pragma unroll
        for (int off = 32; off >= 1; off >>= 1) p += __shfl_xor(p, off, 64);
        float mn = fmaxf(mx, p);
        float sc = __expf(mx - mn), w = __expf(p - mn);
        ssum = ssum * sc + w;
        g0 = g0 * sc + w * h0;
        g1 = g1 * sc + w * h1;
        mx = mn;
    }
    float2 o; o.x = g0 / ssum; o.y = g1 / ssum;
    *(float2*)(gout + (size_t)bg * 128 + 2 * lane) = o;
}

// ---------------- final projection ----------------
__global__ __launch_bounds__(128) void proj_kernel(
    const float* __restrict__ g, const float* __restrict__ W,
    const float* __restrict__ bias, float* __restrict__ out)
{
    int bg = blockIdx.x;
    int o = threadIdx.x;
    const float* gp = g + (size_t)bg * 128;
    float acc = bias[o];
    for (int k = 0; k < 128; k++) acc = fmaf(gp[k], W[k * 128 + o], acc);
    out[(size_t)bg * 128 + o] = acc;
}

extern "C" void kernel_launch(void* const* d_in, const int* in_sizes, int n_in,
                              void* d_out, int out_size, void* d_ws, size_t ws_size,
                              hipStream_t stream)
{
    const float* x     = (const float*)d_in[0];
    const int*   ei    = (const int*)d_in[1];
    const float* Wl1   = (const float*)d_in[3];
    const float* bl1   = (const float*)d_in[4];
    const float* Wr1   = (const float*)d_in[5];
    const float* br1   = (const float*)d_in[6];
    const float* att1  = (const float*)d_in[7];
    const float* bias1 = (const float*)d_in[8];
    const float* Wl2   = (const float*)d_in[9];
    const float* bl2   = (const float*)d_in[10];
    const float* Wr2   = (const float*)d_in[11];
    const float* br2   = (const float*)d_in[12];
    const float* att2  = (const float*)d_in[13];
    const float* bias2 = (const float*)d_in[14];
    const float* ln1g  = (const float*)d_in[15];
    const float* ln1b  = (const float*)d_in[16];
    const float* ln2g  = (const float*)d_in[17];
    const float* ln2b  = (const float*)d_in[18];
    const float* query = (const float*)d_in[19];
    const float* projW = (const float*)d_in[20];
    const float* projb = (const float*)d_in[21];
    float* out = (float*)d_out;

    // workspace layout — all regions rewritten every call
    unsigned short* xlr6 = (unsigned short*)d_ws;                 // 245.76 MB
    unsigned short* h1bf = xlr6 + (size_t)R_REL * N_NODES * 512;  // 10.24 MB
    unsigned short* xbf  = h1bf + (size_t)N_NODES * 128;          // 2.56 MB
    unsigned short* Bt1  = xbf + (size_t)N_NODES * 32;
    unsigned short* Bt2  = Bt1 + R_REL * 512 * 32;
    float* bc1  = (float*)(Bt2 + R_REL * 512 * 128);
    float* bc2  = bc1 + R_REL * 512;
    float* gb   = bc2 + R_REL * 512;                              // 2000*128 f32
    int* cnt    = (int*)(gb + (size_t)B_GRAPHS * 128);            // NB
    int* part   = cnt + NB;                                       // NB
    int* rowptr = part + NB;                                      // NB+1
    int* cursor = rowptr + NB + 1;                                // NB
    int* bsum   = cursor + NB;                                    // NBLK
    int* boff   = bsum + NBLK;                                    // NBLK
    int* csr    = boff + NBLK;                                    // NTOT

    // ---- CSR build ----
    hipMemsetAsync(cnt, 0, sizeof(int) * NB, stream);
    count_kernel<<<(NTOT + 255) / 256, 256, 0, stream>>>(ei, cnt);
    scan1_kernel<<<NBLK, 256, 0, stream>>>(cnt, part, bsum);
    scan2_kernel<<<1, 1024, 0, stream>>>(bsum, boff);
    scan3_kernel<<<NBLK, 256, 0, stream>>>(part, boff, rowptr, cursor);
    scatter_kernel<<<(NTOT + 255) / 256, 256, 0, stream>>>(ei, cursor, csr);

    // ---- prep ----
    cvt_bf16_kernel<<<(N_NODES * 16 + 255) / 256, 256, 0, stream>>>(x, (unsigned*)xbf, N_NODES * 16);
    prep_w_kernel<<<(R_REL * 512 * 32 + 255) / 256, 256, 0, stream>>>(Wl1, Wr1, bl1, br1, Bt1, bc1, 32);
    prep_w_kernel<<<(R_REL * 512 * 128 + 255) / 256, 256, 0, stream>>>(Wl2, Wr2, bl2, br2, Bt2, bc2, 128);

    // ---- layer 1 ----
    dim3 g1((N_NODES + 127) / 128, 4, 1);
    gemm_mfma_kernel<32, 6><<<g1, 256, 0, stream>>>(xbf, Bt1, bc1, xlr6);
    gat6_ln_kernel<<<N_NODES / 4, 256, 0, stream>>>(
        xlr6, rowptr, csr, att1, bias1, ln1g, ln1b, (unsigned*)h1bf);
    // ---- layer 2 ----
    dim3 g2((N_NODES + 127) / 128, 4, 2);
    gemm_mfma_kernel<128, 3><<<g2, 256, 0, stream>>>(h1bf, Bt2, bc2, xlr6);
    gat6_ln_kernel<<<N_NODES / 4, 256, 0, stream>>>(
        xlr6, rowptr, csr, att2, bias2, ln2g, ln2b, (unsigned*)h1bf);
    // ---- pooling + projection ----
    pool_kernel<<<B_GRAPHS / 4, 256, 0, stream>>>((unsigned*)h1bf, query, gb);
    proj_kernel<<<B_GRAPHS, 128, 0, stream>>>(gb, projW, projb, out);
}